// Round 5
// baseline (655.760 us; speedup 1.0000x reference)
//
#include <hip/hip_runtime.h>

// B=2,N=2048,D=256,H=8,HD=32,DFF=1024. SCALE MULTIPLIES by sqrt(32). No MLP
// activation. Post-norm. Inputs fp32 (CONFIRMED R3: bf16-misread NaNs died).
// OUTPUT IS FP32 (R5 theory): the test's "(bf16" label is a hardcoded string;
// reference returns fp32. R3/R4's bit-identical absmax 9.1875 = fp32 readback
// of my packed-bf16 writes (pseudo-field decorrelated from ref: max|diff| of
// two N(0,1.9) fields over 524k elems ~ 9.2; zero tail gives 6.72 < 9.19).
// Single change this round: final GEMM writes fp32 (+bias+residual) to d_out.
//
// ws layout (bytes), peak 16 MB, phase overlays:
//   flag@0  biases@4K..24K  wq_hi@128K wq_lo@512K wt_proj@896K wt_fc1@1M
//   wt_fc2@1.5M | x_hi@2M x_lo@4M q_hi@6M q_lo@8M k_hi@10M k_lo@12M v@14M
//   (end 16M). attn scratch = d_out (first 2MB of its 4MB). projf(fp32)@6M
//   over dead Q; net@14M over dead v; hbuf(8MB)@2M over dead x/projf.

typedef __attribute__((ext_vector_type(8))) short short8;   // 8 bf16 = 4 VGPRs
typedef __attribute__((ext_vector_type(4))) float floatx4;
typedef unsigned short u16;

#define MFMA16(a,b,c) __builtin_amdgcn_mfma_f32_16x16x32_bf16((a),(b),(c),0,0,0)
#define ATT_SCALE 5.656854249492380f

__device__ __forceinline__ float bf2f(u16 u) { return __uint_as_float(((unsigned)u) << 16); }
__device__ __forceinline__ u16 f2bf(float f) {            // RNE
  unsigned u = __float_as_uint(f);
  u += 0x7fffu + ((u >> 16) & 1u);
  return (u16)(u >> 16);
}

// ------- dtype sniff: bf16-interpret qkv_w; fp32 backing -> ~46% |v|>1e3/NaN -------
__global__ void detect_k(const u16* __restrict__ w, int* __restrict__ flag) {
  int bad = 0;
  for (int i = threadIdx.x; i < 16384; i += 64) {
    float f = bf2f(w[i]);
    if (!(fabsf(f) < 1000.0f)) bad = 1;     // catches NaN too
  }
  unsigned long long b = __ballot(bad != 0);
  if (threadIdx.x == 0) *flag = (b != 0ull) ? 1 : 0;
}

// ------- canonicalize: flag ? fp32 : bf16 source -> bf16 hi (+ optional lo) -------
__global__ __launch_bounds__(256) void cvt_k(const void* __restrict__ in,
                                             u16* __restrict__ hi, u16* __restrict__ lo,
                                             const int* __restrict__ flag) {
  const int i = blockIdx.x * 256 + threadIdx.x;
  const float f = (*flag) ? ((const float*)in)[i] : bf2f(((const u16*)in)[i]);
  const u16 h = f2bf(f);
  hi[i] = h;
  if (lo) lo[i] = f2bf(f - bf2f(h));
}

// ------- transpose+canonicalize weights: out[n*K+k] = cvt(in[k*Nn+n]), K=1<<kshift -------
__global__ __launch_bounds__(256) void cvtT_k(const void* __restrict__ in,
                                              u16* __restrict__ hi, u16* __restrict__ lo,
                                              int kshift, int Nn, const int* __restrict__ flag) {
  const int idx = blockIdx.x * 256 + threadIdx.x;
  const int n = idx >> kshift, k = idx & ((1 << kshift) - 1);
  const size_t src = (size_t)k * Nn + n;
  const float f = (*flag) ? ((const float*)in)[src] : bf2f(((const u16*)in)[src]);
  const u16 h = f2bf(f);
  hi[idx] = h;
  if (lo) lo[idx] = f2bf(f - bf2f(h));
}

// ---------------- GEMM: C[M,Nn] = A[M,K] * Bt[Nn,K]^T  (bf16, fp32 accum) -----------
// TW: wave tile = TW*16 square; block = 2x2 waves -> block tile 32*TW.
// EPI: 0 fp32 out, 1 bf16 out, 2 qkv split (q hi/lo, k hi/lo, v plain).
// SPLIT: A,B have hi/lo pairs -> 3-term MFMA, ~fp32-accurate product.
template<int TW, int EPI, bool BIAS, bool RES, bool SPLIT>
__global__ __launch_bounds__(256) void gemm_k(
    const u16* __restrict__ A, const u16* __restrict__ Bt,
    const u16* __restrict__ A2, const u16* __restrict__ B2,
    const u16* __restrict__ bias, const u16* __restrict__ res,
    void* __restrict__ out0, u16* __restrict__ aux1, u16* __restrict__ aux2,
    u16* __restrict__ aux3, u16* __restrict__ aux4,
    int M, int Nn, int K)
{
  constexpr int BT = TW * 32;
  __shared__ __align__(16) short As[BT][40];   // pad 32->40: 16B frag alignment kept
  __shared__ __align__(16) short Bs[BT][40];
  __shared__ __align__(16) short As2[SPLIT ? BT : 1][40];
  __shared__ __align__(16) short Bs2[SPLIT ? BT : 1][40];
  const int tid = threadIdx.x;
  const int m0 = blockIdx.y * BT, n0 = blockIdx.x * BT;
  const int wid = tid >> 6, lane = tid & 63;
  const int wm = (wid >> 1) * (TW * 16), wn = (wid & 1) * (TW * 16);
  const int lm = lane & 15, quad = lane >> 4;

  floatx4 zero = {0.f, 0.f, 0.f, 0.f};
  floatx4 acc[TW][TW];
#pragma unroll
  for (int i = 0; i < TW; ++i)
#pragma unroll
    for (int j = 0; j < TW; ++j) acc[i][j] = zero;

  for (int k0 = 0; k0 < K; k0 += 32) {
#pragma unroll
    for (int c = 0; c < TW / 2; ++c) {
      int cid = tid * (TW / 2) + c;
      int row = cid >> 2, off = (cid & 3) * 8;
      const size_t ga = (size_t)(m0 + row) * K + k0 + off;
      const size_t gb = (size_t)(n0 + row) * K + k0 + off;
      *(short8*)&As[row][off] = *(const short8*)&A[ga];
      *(short8*)&Bs[row][off] = *(const short8*)&Bt[gb];
      if (SPLIT) {
        *(short8*)&As2[row][off] = *(const short8*)&A2[ga];
        *(short8*)&Bs2[row][off] = *(const short8*)&B2[gb];
      }
    }
    __syncthreads();
    short8 fa[TW], fb[TW], fa2[TW], fb2[TW];
#pragma unroll
    for (int t = 0; t < TW; ++t) {
      fa[t] = *(const short8*)&As[wm + t * 16 + lm][quad * 8];  // A[m=lane&15][k=quad*8+j]
      fb[t] = *(const short8*)&Bs[wn + t * 16 + lm][quad * 8];  // B^T[n=lane&15][k=...]
      if (SPLIT) {
        fa2[t] = *(const short8*)&As2[wm + t * 16 + lm][quad * 8];
        fb2[t] = *(const short8*)&Bs2[wn + t * 16 + lm][quad * 8];
      }
    }
#pragma unroll
    for (int i = 0; i < TW; ++i)
#pragma unroll
      for (int j = 0; j < TW; ++j) {
        if (SPLIT) {
          acc[i][j] = MFMA16(fa[i], fb2[j], acc[i][j]);
          acc[i][j] = MFMA16(fa2[i], fb[j], acc[i][j]);
        }
        acc[i][j] = MFMA16(fa[i], fb[j], acc[i][j]);
      }
    __syncthreads();
  }

  // epilogue: C/D layout col=lane&15, row=quad*4+reg (m89/m91 verified)
#pragma unroll
  for (int i = 0; i < TW; ++i) {
    const int rowb = m0 + wm + i * 16 + quad * 4;
#pragma unroll
    for (int j = 0; j < TW; ++j) {
      const int col = n0 + wn + j * 16 + lm;
      const float bv = BIAS ? bf2f(bias[col]) : 0.f;
#pragma unroll
      for (int r = 0; r < 4; ++r) {
        const int row = rowb + r;
        float v = acc[i][j][r] + bv;
        const size_t o = (size_t)row * Nn + col;
        if (RES) v += bf2f(res[o]);
        if (EPI == 0) {
          ((float*)out0)[o] = v;
        } else if (EPI == 1) {
          ((u16*)out0)[o] = f2bf(v);
        } else {
          u16 hi = f2bf(v);
          u16 lo = f2bf(v - bf2f(hi));          // lo residual: QK scores ~fp32-accurate
          if (col < 256) {
            const size_t oq = (size_t)row * 256 + col;
            aux1[oq] = hi; aux2[oq] = lo;       // Q
          } else if (col < 512) {
            const size_t ok = (size_t)row * 256 + (col - 256);
            aux3[ok] = hi; aux4[ok] = lo;       // K
          } else {                              // V -> plain [4096][256] rows
            ((u16*)out0)[(size_t)row * 256 + (col - 512)] = hi;
          }
        }
      }
    }
  }
}

// ------- attention: pure fp32 VALU, layout-free (kept from R4 for the controlled test) -------
// Block = 256 threads = 4 waves; block handles 8 q rows of one (b,h); wave w
// owns rows q0+w*2+{0,1}. K/V staged per 64-key tile into padded fp32 LDS.
__global__ __launch_bounds__(256) void attn_diag_k(
    const u16* __restrict__ qhi, const u16* __restrict__ qlo,
    const u16* __restrict__ khi, const u16* __restrict__ klo,
    const u16* __restrict__ v, u16* __restrict__ attn)
{
  __shared__ float Kf[64][33];   // +1 pad
  __shared__ float Vf[64][33];
  __shared__ float qf[8][32];
  const int tid = threadIdx.x, lane = tid & 63, w = tid >> 6;
  const int bh = blockIdx.x >> 8, qg = blockIdx.x & 255;
  const int b = bh >> 3, h = bh & 7;
  const int q0 = qg * 8;
  const size_t tb = (size_t)b * 2048;

  {  // stage 8 q rows as fp32 (hi+lo)
    const int qr = tid >> 5, d = tid & 31;
    const size_t o = (tb + q0 + qr) * 256 + h * 32 + d;
    qf[qr][d] = bf2f(qhi[o]) + bf2f(qlo[o]);
  }

  float mr[2] = {-1e30f, -1e30f}, lr[2] = {0.f, 0.f};
  float op[2][32];
#pragma unroll
  for (int r = 0; r < 2; ++r)
#pragma unroll
    for (int d = 0; d < 32; ++d) op[r][d] = 0.f;

  for (int kt = 0; kt < 32; ++kt) {
    __syncthreads();                       // protect prev-iter Kf/Vf reads (and qf 1st iter)
#pragma unroll
    for (int e = 0; e < 8; ++e) {          // stage 64x32 K (fp32 = hi+lo) and V
      const int idx = tid * 8 + e;
      const int key = idx >> 5, d = idx & 31;
      const size_t o = (tb + kt * 64 + key) * 256 + h * 32 + d;
      Kf[key][d] = bf2f(khi[o]) + bf2f(klo[o]);
      Vf[key][d] = bf2f(v[o]);
    }
    __syncthreads();
#pragma unroll
    for (int r = 0; r < 2; ++r) {
      const float* q = qf[w * 2 + r];
      float s = 0.f;
#pragma unroll
      for (int d = 0; d < 32; ++d) s += q[d] * Kf[lane][d];
      s *= ATT_SCALE;
      float tmax = s;
#pragma unroll
      for (int dd = 1; dd < 64; dd <<= 1) tmax = fmaxf(tmax, __shfl_xor(tmax, dd));
      const float mn = fmaxf(mr[r], tmax);
      const float al = __expf(mr[r] - mn);
      mr[r] = mn;
      const float p = __expf(s - mn);
      float ts = p;
#pragma unroll
      for (int dd = 1; dd < 64; dd <<= 1) ts += __shfl_xor(ts, dd);
      lr[r] = lr[r] * al + ts;
#pragma unroll
      for (int d = 0; d < 32; ++d) op[r][d] = op[r][d] * al + p * Vf[lane][d];
    }
  }
  // reduce per-lane partials over the wave; lane d keeps dim d
#pragma unroll
  for (int r = 0; r < 2; ++r) {
    float keep = 0.f;
#pragma unroll
    for (int d = 0; d < 32; ++d) {
      float vv = op[r][d];
#pragma unroll
      for (int dd = 1; dd < 64; dd <<= 1) vv += __shfl_xor(vv, dd);
      if (lane == d) keep = vv;
    }
    if (lane < 32) {
      const size_t row = tb + q0 + w * 2 + r;
      attn[row * 256 + h * 32 + lane] = f2bf(keep / lr[r]);
    }
  }
}

// ---------------- residual add + LayerNorm: net = LN(projf + x) ----------------
__global__ __launch_bounds__(256) void ln_k(const float* __restrict__ pf,
                                            const u16* __restrict__ xh,
                                            const u16* __restrict__ xl,
                                            const u16* __restrict__ g,
                                            const u16* __restrict__ bta,
                                            u16* __restrict__ net)
{
  const int t = blockIdx.x, c = threadIdx.x;
  const size_t o = (size_t)t * 256 + c;
  float v = pf[o] + bf2f(xh[o]) + bf2f(xl[o]);
  float s = v, s2 = v * v;
#pragma unroll
  for (int d = 1; d < 64; d <<= 1) { s += __shfl_xor(s, d); s2 += __shfl_xor(s2, d); }
  __shared__ float ss[4], ss2[4];
  const int w = c >> 6;
  if ((c & 63) == 0) { ss[w] = s; ss2[w] = s2; }
  __syncthreads();
  s = ss[0] + ss[1] + ss[2] + ss[3];
  s2 = ss2[0] + ss2[1] + ss2[2] + ss2[3];
  const float mu = s * (1.f / 256.f);
  const float var = s2 * (1.f / 256.f) - mu * mu;
  const float is = rsqrtf(var + 1e-5f);
  net[o] = f2bf((v - mu) * is * bf2f(g[c]) + bf2f(bta[c]));
}

extern "C" void kernel_launch(void* const* d_in, const int* in_sizes, int n_in,
                              void* d_out, int out_size, void* d_ws, size_t ws_size,
                              hipStream_t stream) {
  const void* x      = d_in[0];
  const void* qkv_w  = d_in[1];
  const void* proj_w = d_in[2];
  const void* proj_b = d_in[3];
  const void* fc1_w  = d_in[4];
  const void* fc1_b  = d_in[5];
  const void* fc2_w  = d_in[6];
  const void* fc2_b  = d_in[7];
  const void* ln_g   = d_in[8];
  const void* ln_b   = d_in[9];

  char* ws = (char*)d_ws;
  int* flag    = (int*)(ws);
  u16* b_proj  = (u16*)(ws + 4096);
  u16* b_fc1   = (u16*)(ws + 8192);
  u16* b_fc2   = (u16*)(ws + 12288);
  u16* g_ln    = (u16*)(ws + 16384);
  u16* bb_ln   = (u16*)(ws + 20480);
  u16* wq_hi   = (u16*)(ws + 131072);    // [768][256]
  u16* wq_lo   = (u16*)(ws + 524288);
  u16* wt_proj = (u16*)(ws + 917504);    // [256][256]
  u16* wt_fc1  = (u16*)(ws + 1048576);   // [1024][256]
  u16* wt_fc2  = (u16*)(ws + 1572864);   // [256][1024]
  u16* x_hi    = (u16*)(ws + 2097152);   // [4096][256]
  u16* x_lo    = (u16*)(ws + 4194304);
  u16* q_hi    = (u16*)(ws + 6291456);
  u16* q_lo    = (u16*)(ws + 8388608);
  u16* k_hi    = (u16*)(ws + 10485760);
  u16* k_lo    = (u16*)(ws + 12582912);
  u16* v_buf   = (u16*)(ws + 14680064);  // [4096][256] plain V; end 16MB
  u16* attn    = (u16*)d_out;            // first 2MB of d_out = attn scratch (bf16)
  float* projf = (float*)(ws + 6291456); // 4MB fp32 over dead Q
  u16* net     = (u16*)(ws + 14680064);  // 2MB over dead v_buf
  u16* hbuf    = (u16*)(ws + 2097152);   // 8MB over dead x/projf

  detect_k<<<1, 64, 0, stream>>>((const u16*)qkv_w, flag);
  cvt_k<<<4096, 256, 0, stream>>>(x, x_hi, x_lo, flag);
  cvtT_k<<<768, 256, 0, stream>>>(qkv_w, wq_hi, wq_lo, 8, 768, flag);
  cvtT_k<<<256, 256, 0, stream>>>(proj_w, wt_proj, nullptr, 8, 256, flag);
  cvtT_k<<<1024, 256, 0, stream>>>(fc1_w, wt_fc1, nullptr, 8, 1024, flag);
  cvtT_k<<<1024, 256, 0, stream>>>(fc2_w, wt_fc2, nullptr, 10, 256, flag);
  cvt_k<<<1, 256, 0, stream>>>(proj_b, b_proj, nullptr, flag);
  cvt_k<<<4, 256, 0, stream>>>(fc1_b, b_fc1, nullptr, flag);
  cvt_k<<<1, 256, 0, stream>>>(fc2_b, b_fc2, nullptr, flag);
  cvt_k<<<1, 256, 0, stream>>>(ln_g, g_ln, nullptr, flag);
  cvt_k<<<1, 256, 0, stream>>>(ln_b, bb_ln, nullptr, flag);

  // qkv = x @ qkv_w, 3-term hi/lo -> q hi/lo (aux1,2), k hi/lo (aux3,4), v plain (out0)
  gemm_k<4, 2, false, false, true><<<dim3(6, 32), 256, 0, stream>>>(
      x_hi, wq_hi, x_lo, wq_lo, nullptr, nullptr, v_buf, q_hi, q_lo, k_hi, k_lo, 4096, 768, 256);
  attn_diag_k<<<4096, 256, 0, stream>>>(q_hi, q_lo, k_hi, k_lo, v_buf, attn);
  // proj (+bias) -> fp32
  gemm_k<2, 0, true, false, false><<<dim3(4, 64), 256, 0, stream>>>(
      attn, wt_proj, nullptr, nullptr, b_proj, nullptr, projf,
      nullptr, nullptr, nullptr, nullptr, 4096, 256, 256);
  ln_k<<<4096, 256, 0, stream>>>(projf, x_hi, x_lo, g_ln, bb_ln, net);
  // fc1 (+bias)
  gemm_k<4, 1, true, false, false><<<dim3(8, 32), 256, 0, stream>>>(
      net, wt_fc1, nullptr, nullptr, b_fc1, nullptr, hbuf,
      nullptr, nullptr, nullptr, nullptr, 4096, 1024, 256);
  // fc2 (+bias +shortcut) -> d_out FP32  <-- the R5 change
  gemm_k<2, 0, true, true, false><<<dim3(4, 64), 256, 0, stream>>>(
      hbuf, wt_fc2, nullptr, nullptr, b_fc2, net, d_out,
      nullptr, nullptr, nullptr, nullptr, 4096, 256, 1024);
}

// Round 6
// 270.986 us; speedup vs baseline: 2.4199x; 2.4199x over previous
//
#include <hip/hip_runtime.h>

// B=2,N=2048,D=256,H=8,HD=32,DFF=1024. SCALE MULTIPLIES by sqrt(32). No MLP
// activation. Post-norm. Inputs fp32, OUTPUT fp32 (CONFIRMED R5: passed,
// absmax 0.031). R6: swap the 523us scalar diagnostic attention back to the
// MFMA flash attention (R3 version — retroactively validated by R3/R4
// bit-identical outputs). qkv epilogue writes per-head-transposed V again.
//
// ws layout (bytes), peak 16 MB, phase overlays:
//   flag@0  biases@4K..24K  wq_hi@128K wq_lo@512K wt_proj@896K wt_fc1@1M
//   wt_fc2@1.5M | x_hi@2M x_lo@4M q_hi@6M q_lo@8M k_hi@10M k_lo@12M vt@14M
//   (end 16M). attn scratch = d_out (first 2MB of its 4MB). projf(fp32)@6M
//   over dead Q; net@14M over dead vt; hbuf(8MB)@2M over dead x/projf.

typedef __attribute__((ext_vector_type(8))) short short8;   // 8 bf16 = 4 VGPRs
typedef __attribute__((ext_vector_type(4))) float floatx4;
typedef unsigned short u16;

#define MFMA16(a,b,c) __builtin_amdgcn_mfma_f32_16x16x32_bf16((a),(b),(c),0,0,0)
#define ATT_SCALE 5.656854249492380f

__device__ __forceinline__ float bf2f(u16 u) { return __uint_as_float(((unsigned)u) << 16); }
__device__ __forceinline__ u16 f2bf(float f) {            // RNE
  unsigned u = __float_as_uint(f);
  u += 0x7fffu + ((u >> 16) & 1u);
  return (u16)(u >> 16);
}

// ------- dtype sniff: bf16-interpret qkv_w; fp32 backing -> ~46% |v|>1e3/NaN -------
__global__ void detect_k(const u16* __restrict__ w, int* __restrict__ flag) {
  int bad = 0;
  for (int i = threadIdx.x; i < 16384; i += 64) {
    float f = bf2f(w[i]);
    if (!(fabsf(f) < 1000.0f)) bad = 1;     // catches NaN too
  }
  unsigned long long b = __ballot(bad != 0);
  if (threadIdx.x == 0) *flag = (b != 0ull) ? 1 : 0;
}

// ------- canonicalize: flag ? fp32 : bf16 source -> bf16 hi (+ optional lo) -------
__global__ __launch_bounds__(256) void cvt_k(const void* __restrict__ in,
                                             u16* __restrict__ hi, u16* __restrict__ lo,
                                             const int* __restrict__ flag) {
  const int i = blockIdx.x * 256 + threadIdx.x;
  const float f = (*flag) ? ((const float*)in)[i] : bf2f(((const u16*)in)[i]);
  const u16 h = f2bf(f);
  hi[i] = h;
  if (lo) lo[i] = f2bf(f - bf2f(h));
}

// ------- transpose+canonicalize weights: out[n*K+k] = cvt(in[k*Nn+n]), K=1<<kshift -------
__global__ __launch_bounds__(256) void cvtT_k(const void* __restrict__ in,
                                              u16* __restrict__ hi, u16* __restrict__ lo,
                                              int kshift, int Nn, const int* __restrict__ flag) {
  const int idx = blockIdx.x * 256 + threadIdx.x;
  const int n = idx >> kshift, k = idx & ((1 << kshift) - 1);
  const size_t src = (size_t)k * Nn + n;
  const float f = (*flag) ? ((const float*)in)[src] : bf2f(((const u16*)in)[src]);
  const u16 h = f2bf(f);
  hi[idx] = h;
  if (lo) lo[idx] = f2bf(f - bf2f(h));
}

// ---------------- GEMM: C[M,Nn] = A[M,K] * Bt[Nn,K]^T  (bf16, fp32 accum) -----------
// TW: wave tile = TW*16 square; block = 2x2 waves -> block tile 32*TW.
// EPI: 0 fp32 out, 1 bf16 out, 2 qkv split (q hi/lo, k hi/lo, vt transposed).
// SPLIT: A,B have hi/lo pairs -> 3-term MFMA, ~fp32-accurate product.
template<int TW, int EPI, bool BIAS, bool RES, bool SPLIT>
__global__ __launch_bounds__(256) void gemm_k(
    const u16* __restrict__ A, const u16* __restrict__ Bt,
    const u16* __restrict__ A2, const u16* __restrict__ B2,
    const u16* __restrict__ bias, const u16* __restrict__ res,
    void* __restrict__ out0, u16* __restrict__ aux1, u16* __restrict__ aux2,
    u16* __restrict__ aux3, u16* __restrict__ aux4,
    int M, int Nn, int K)
{
  constexpr int BT = TW * 32;
  __shared__ __align__(16) short As[BT][40];   // pad 32->40: 16B frag alignment kept
  __shared__ __align__(16) short Bs[BT][40];
  __shared__ __align__(16) short As2[SPLIT ? BT : 1][40];
  __shared__ __align__(16) short Bs2[SPLIT ? BT : 1][40];
  const int tid = threadIdx.x;
  const int m0 = blockIdx.y * BT, n0 = blockIdx.x * BT;
  const int wid = tid >> 6, lane = tid & 63;
  const int wm = (wid >> 1) * (TW * 16), wn = (wid & 1) * (TW * 16);
  const int lm = lane & 15, quad = lane >> 4;

  floatx4 zero = {0.f, 0.f, 0.f, 0.f};
  floatx4 acc[TW][TW];
#pragma unroll
  for (int i = 0; i < TW; ++i)
#pragma unroll
    for (int j = 0; j < TW; ++j) acc[i][j] = zero;

  for (int k0 = 0; k0 < K; k0 += 32) {
#pragma unroll
    for (int c = 0; c < TW / 2; ++c) {
      int cid = tid * (TW / 2) + c;
      int row = cid >> 2, off = (cid & 3) * 8;
      const size_t ga = (size_t)(m0 + row) * K + k0 + off;
      const size_t gb = (size_t)(n0 + row) * K + k0 + off;
      *(short8*)&As[row][off] = *(const short8*)&A[ga];
      *(short8*)&Bs[row][off] = *(const short8*)&Bt[gb];
      if (SPLIT) {
        *(short8*)&As2[row][off] = *(const short8*)&A2[ga];
        *(short8*)&Bs2[row][off] = *(const short8*)&B2[gb];
      }
    }
    __syncthreads();
    short8 fa[TW], fb[TW], fa2[TW], fb2[TW];
#pragma unroll
    for (int t = 0; t < TW; ++t) {
      fa[t] = *(const short8*)&As[wm + t * 16 + lm][quad * 8];  // A[m=lane&15][k=quad*8+j]
      fb[t] = *(const short8*)&Bs[wn + t * 16 + lm][quad * 8];  // B^T[n=lane&15][k=...]
      if (SPLIT) {
        fa2[t] = *(const short8*)&As2[wm + t * 16 + lm][quad * 8];
        fb2[t] = *(const short8*)&Bs2[wn + t * 16 + lm][quad * 8];
      }
    }
#pragma unroll
    for (int i = 0; i < TW; ++i)
#pragma unroll
      for (int j = 0; j < TW; ++j) {
        if (SPLIT) {
          acc[i][j] = MFMA16(fa[i], fb2[j], acc[i][j]);
          acc[i][j] = MFMA16(fa2[i], fb[j], acc[i][j]);
        }
        acc[i][j] = MFMA16(fa[i], fb[j], acc[i][j]);
      }
    __syncthreads();
  }

  // epilogue: C/D layout col=lane&15, row=quad*4+reg (m89/m91 verified)
#pragma unroll
  for (int i = 0; i < TW; ++i) {
    const int rowb = m0 + wm + i * 16 + quad * 4;
#pragma unroll
    for (int j = 0; j < TW; ++j) {
      const int col = n0 + wn + j * 16 + lm;
      const float bv = BIAS ? bf2f(bias[col]) : 0.f;
#pragma unroll
      for (int r = 0; r < 4; ++r) {
        const int row = rowb + r;
        float v = acc[i][j][r] + bv;
        const size_t o = (size_t)row * Nn + col;
        if (RES) v += bf2f(res[o]);
        if (EPI == 0) {
          ((float*)out0)[o] = v;
        } else if (EPI == 1) {
          ((u16*)out0)[o] = f2bf(v);
        } else {
          u16 hi = f2bf(v);
          u16 lo = f2bf(v - bf2f(hi));          // lo residual: QK scores ~fp32-accurate
          if (col < 256) {
            const size_t oq = (size_t)row * 256 + col;
            aux1[oq] = hi; aux2[oq] = lo;       // Q
          } else if (col < 512) {
            const size_t ok = (size_t)row * 256 + (col - 256);
            aux3[ok] = hi; aux4[ok] = lo;       // K
          } else {                              // V -> per-head transposed copy
            int d = col & 31, hh = (col >> 5) & 7;
            int bb = row >> 11, n = row & 2047;
            ((u16*)out0)[(size_t)((bb * 8 + hh) * 32 + d) * 2048 + n] = hi;
          }
        }
      }
    }
  }
}

// ---------------- flash attention: wave = 16 q rows; block = 4 waves sharing K/V tiles ----
__global__ __launch_bounds__(256) void attn_k(
    const u16* __restrict__ qhi, const u16* __restrict__ qlo,
    const u16* __restrict__ khi, const u16* __restrict__ klo,
    const u16* __restrict__ vt, u16* __restrict__ attn)
{
  __shared__ __align__(16) short Ksh[64][40], Ksl[64][40];  // K tile (hi/lo), row=key, col=d
  __shared__ __align__(16) short Vs[32][72];                // V tile transposed: row=d, col=key
  __shared__ __align__(16) short Ps[4][16][72];             // per-wave P (C-layout -> A-layout)
  const int tid = threadIdx.x, wid = tid >> 6, lane = tid & 63;
  const int lm = lane & 15, quad = lane >> 4;
  const int bid = blockIdx.x;
  const int qblk = bid & 31, bh = bid >> 5;                 // 32 q-blocks x 16 (b,h)
  const int b = bh >> 3, h = bh & 7;
  const int q0 = qblk * 64 + wid * 16;
  const size_t tb = (size_t)b * 2048;

  short8 qh, ql;
  {
    size_t off = (tb + q0 + lm) * 256 + h * 32 + quad * 8;  // Q A-frag, persistent
    qh = *(const short8*)&qhi[off];
    ql = *(const short8*)&qlo[off];
  }
  float mrun[4], lrun[4];
  floatx4 o0 = {0.f,0.f,0.f,0.f}, o1 = {0.f,0.f,0.f,0.f};
#pragma unroll
  for (int r = 0; r < 4; ++r) { mrun[r] = -1e30f; lrun[r] = 0.f; }

  const int srow = tid >> 2, soff = (tid & 3) * 8;          // K staging: 64 keys x 32 d
  const int vd = tid >> 3, vkoff = (tid & 7) * 8;           // V staging: 32 d x 64 keys
  const size_t vrow = (size_t)(bh * 32 + vd) * 2048;

  for (int kt = 0; kt < 32; ++kt) {
    const int key0 = kt * 64;
    __syncthreads();
    {
      size_t off = (tb + key0 + srow) * 256 + h * 32 + soff;
      *(short8*)&Ksh[srow][soff] = *(const short8*)&khi[off];
      *(short8*)&Ksl[srow][soff] = *(const short8*)&klo[off];
      *(short8*)&Vs[vd][vkoff]   = *(const short8*)&vt[vrow + key0 + vkoff];
    }
    __syncthreads();

    // S = (qh*kh + qh*kl + ql*kh) * SCALE   (drop ql*kl ~ 2^-18)
    floatx4 s[4];
#pragma unroll
    for (int kf = 0; kf < 4; ++kf) {
      short8 kh = *(const short8*)&Ksh[kf * 16 + lm][quad * 8];
      short8 kl = *(const short8*)&Ksl[kf * 16 + lm][quad * 8];
      floatx4 z = {0.f,0.f,0.f,0.f};
      z = MFMA16(qh, kl, z);
      z = MFMA16(ql, kh, z);
      z = MFMA16(qh, kh, z);
      s[kf] = z * ATT_SCALE;
    }
    // online softmax; row = quad*4+r, cols spread over the 16 lanes of the quad
    float rmax[4];
#pragma unroll
    for (int r = 0; r < 4; ++r)
      rmax[r] = fmaxf(fmaxf(s[0][r], s[1][r]), fmaxf(s[2][r], s[3][r]));
#pragma unroll
    for (int r = 0; r < 4; ++r)
#pragma unroll
      for (int d = 1; d < 16; d <<= 1)
        rmax[r] = fmaxf(rmax[r], __shfl_xor(rmax[r], d, 16));
    float alpha[4], rsum[4];
#pragma unroll
    for (int r = 0; r < 4; ++r) {
      float mn = fmaxf(mrun[r], rmax[r]);
      alpha[r] = __expf(mrun[r] - mn);
      mrun[r] = mn;
      rsum[r] = 0.f;
    }
#pragma unroll
    for (int kf = 0; kf < 4; ++kf)
#pragma unroll
      for (int r = 0; r < 4; ++r) {
        float p = __expf(s[kf][r] - mrun[r]);
        s[kf][r] = p;
        rsum[r] += p;
      }
#pragma unroll
    for (int r = 0; r < 4; ++r) {
#pragma unroll
      for (int d = 1; d < 16; d <<= 1)
        rsum[r] += __shfl_xor(rsum[r], d, 16);
      lrun[r] = lrun[r] * alpha[r] + rsum[r];
      o0[r] *= alpha[r];
      o1[r] *= alpha[r];
    }
    // P (C-layout) -> LDS -> A-layout (m120-verified transform)
#pragma unroll
    for (int kf = 0; kf < 4; ++kf)
#pragma unroll
      for (int r = 0; r < 4; ++r)
        Ps[wid][quad * 4 + r][kf * 16 + lm] = (short)f2bf(s[kf][r]);
    __syncthreads();
    short8 p0  = *(const short8*)&Ps[wid][lm][quad * 8];        // keys 0..31
    short8 p1  = *(const short8*)&Ps[wid][lm][32 + quad * 8];   // keys 32..63
    short8 v00 = *(const short8*)&Vs[lm][quad * 8];             // kc0, d 0..15
    short8 v01 = *(const short8*)&Vs[16 + lm][quad * 8];        // kc0, d 16..31
    short8 v10 = *(const short8*)&Vs[lm][32 + quad * 8];        // kc1, d 0..15
    short8 v11 = *(const short8*)&Vs[16 + lm][32 + quad * 8];   // kc1, d 16..31
    o0 = MFMA16(p0, v00, o0);
    o0 = MFMA16(p1, v10, o0);
    o1 = MFMA16(p0, v01, o1);
    o1 = MFMA16(p1, v11, o1);
  }
#pragma unroll
  for (int r = 0; r < 4; ++r) {
    const float inv = 1.0f / lrun[r];
    const size_t row = tb + q0 + quad * 4 + r;
    attn[row * 256 + h * 32 + lm]      = f2bf(o0[r] * inv);
    attn[row * 256 + h * 32 + 16 + lm] = f2bf(o1[r] * inv);
  }
}

// ---------------- residual add + LayerNorm: net = LN(projf + x) ----------------
__global__ __launch_bounds__(256) void ln_k(const float* __restrict__ pf,
                                            const u16* __restrict__ xh,
                                            const u16* __restrict__ xl,
                                            const u16* __restrict__ g,
                                            const u16* __restrict__ bta,
                                            u16* __restrict__ net)
{
  const int t = blockIdx.x, c = threadIdx.x;
  const size_t o = (size_t)t * 256 + c;
  float v = pf[o] + bf2f(xh[o]) + bf2f(xl[o]);
  float s = v, s2 = v * v;
#pragma unroll
  for (int d = 1; d < 64; d <<= 1) { s += __shfl_xor(s, d); s2 += __shfl_xor(s2, d); }
  __shared__ float ss[4], ss2[4];
  const int w = c >> 6;
  if ((c & 63) == 0) { ss[w] = s; ss2[w] = s2; }
  __syncthreads();
  s = ss[0] + ss[1] + ss[2] + ss[3];
  s2 = ss2[0] + ss2[1] + ss2[2] + ss2[3];
  const float mu = s * (1.f / 256.f);
  const float var = s2 * (1.f / 256.f) - mu * mu;
  const float is = rsqrtf(var + 1e-5f);
  net[o] = f2bf((v - mu) * is * bf2f(g[c]) + bf2f(bta[c]));
}

extern "C" void kernel_launch(void* const* d_in, const int* in_sizes, int n_in,
                              void* d_out, int out_size, void* d_ws, size_t ws_size,
                              hipStream_t stream) {
  const void* x      = d_in[0];
  const void* qkv_w  = d_in[1];
  const void* proj_w = d_in[2];
  const void* proj_b = d_in[3];
  const void* fc1_w  = d_in[4];
  const void* fc1_b  = d_in[5];
  const void* fc2_w  = d_in[6];
  const void* fc2_b  = d_in[7];
  const void* ln_g   = d_in[8];
  const void* ln_b   = d_in[9];

  char* ws = (char*)d_ws;
  int* flag    = (int*)(ws);
  u16* b_proj  = (u16*)(ws + 4096);
  u16* b_fc1   = (u16*)(ws + 8192);
  u16* b_fc2   = (u16*)(ws + 12288);
  u16* g_ln    = (u16*)(ws + 16384);
  u16* bb_ln   = (u16*)(ws + 20480);
  u16* wq_hi   = (u16*)(ws + 131072);    // [768][256]
  u16* wq_lo   = (u16*)(ws + 524288);
  u16* wt_proj = (u16*)(ws + 917504);    // [256][256]
  u16* wt_fc1  = (u16*)(ws + 1048576);   // [1024][256]
  u16* wt_fc2  = (u16*)(ws + 1572864);   // [256][1024]
  u16* x_hi    = (u16*)(ws + 2097152);   // [4096][256]
  u16* x_lo    = (u16*)(ws + 4194304);
  u16* q_hi    = (u16*)(ws + 6291456);
  u16* q_lo    = (u16*)(ws + 8388608);
  u16* k_hi    = (u16*)(ws + 10485760);
  u16* k_lo    = (u16*)(ws + 12582912);
  u16* vt      = (u16*)(ws + 14680064);  // [16 bh][32 d][2048 n]; end 16MB
  u16* attn    = (u16*)d_out;            // first 2MB of d_out = attn scratch (bf16)
  float* projf = (float*)(ws + 6291456); // 4MB fp32 over dead Q
  u16* net     = (u16*)(ws + 14680064);  // 2MB over dead vt
  u16* hbuf    = (u16*)(ws + 2097152);   // 8MB over dead x/projf

  detect_k<<<1, 64, 0, stream>>>((const u16*)qkv_w, flag);
  cvt_k<<<4096, 256, 0, stream>>>(x, x_hi, x_lo, flag);
  cvtT_k<<<768, 256, 0, stream>>>(qkv_w, wq_hi, wq_lo, 8, 768, flag);
  cvtT_k<<<256, 256, 0, stream>>>(proj_w, wt_proj, nullptr, 8, 256, flag);
  cvtT_k<<<1024, 256, 0, stream>>>(fc1_w, wt_fc1, nullptr, 8, 1024, flag);
  cvtT_k<<<1024, 256, 0, stream>>>(fc2_w, wt_fc2, nullptr, 10, 256, flag);
  cvt_k<<<1, 256, 0, stream>>>(proj_b, b_proj, nullptr, flag);
  cvt_k<<<4, 256, 0, stream>>>(fc1_b, b_fc1, nullptr, flag);
  cvt_k<<<1, 256, 0, stream>>>(fc2_b, b_fc2, nullptr, flag);
  cvt_k<<<1, 256, 0, stream>>>(ln_g, g_ln, nullptr, flag);
  cvt_k<<<1, 256, 0, stream>>>(ln_b, bb_ln, nullptr, flag);

  // qkv = x @ qkv_w, 3-term hi/lo -> q hi/lo (aux1,2), k hi/lo (aux3,4), vt (out0)
  gemm_k<4, 2, false, false, true><<<dim3(6, 32), 256, 0, stream>>>(
      x_hi, wq_hi, x_lo, wq_lo, nullptr, nullptr, vt, q_hi, q_lo, k_hi, k_lo, 4096, 768, 256);
  attn_k<<<512, 256, 0, stream>>>(q_hi, q_lo, k_hi, k_lo, vt, attn);
  // proj (+bias) -> fp32
  gemm_k<2, 0, true, false, false><<<dim3(4, 64), 256, 0, stream>>>(
      attn, wt_proj, nullptr, nullptr, b_proj, nullptr, projf,
      nullptr, nullptr, nullptr, nullptr, 4096, 256, 256);
  ln_k<<<4096, 256, 0, stream>>>(projf, x_hi, x_lo, g_ln, bb_ln, net);
  // fc1 (+bias)
  gemm_k<4, 1, true, false, false><<<dim3(8, 32), 256, 0, stream>>>(
      net, wt_fc1, nullptr, nullptr, b_fc1, nullptr, hbuf,
      nullptr, nullptr, nullptr, nullptr, 4096, 1024, 256);
  // fc2 (+bias +shortcut) -> d_out fp32
  gemm_k<2, 0, true, true, false><<<dim3(4, 64), 256, 0, stream>>>(
      hbuf, wt_fc2, nullptr, nullptr, b_fc2, net, d_out,
      nullptr, nullptr, nullptr, nullptr, 4096, 256, 1024);
}

// Round 8
// 203.200 us; speedup vs baseline: 3.2272x; 1.3336x over previous
//
#include <hip/hip_runtime.h>

// B=2,N=2048,D=256,H=8,HD=32,DFF=1024. SCALE MULTIPLIES by sqrt(32). No MLP
// activation. Post-norm. Inputs fp32 (auto-detected, per-wave ballot), output
// fp32. Verified R5/R6: absmax 0.031 vs threshold 0.134.
//
// R8 = R7 with the short4 typedef renamed (collided with HIP's built-in).
// R7: (1) preamble 11 launches -> 1 prep_k. (2) attn_k v2: global_load_lds
// double-buffered staging (1 barrier/iter, loads overlap compute), XOR-granule
// swizzle on GLOBAL addrs (LDS dest stays base+lane*16 per m104; frag reads
// 2-way = free per m136), P via Pst[key][qrow] b64 writes, row-sum l via
// ones-MFMA (kills 16 shuffle-adds/iter), grid 512->1024 (2-wave blocks).
//
// ws layout unchanged from R6 (peak 16 MB, phase overlays).

typedef __attribute__((ext_vector_type(8))) short short8;   // 8 bf16 = 4 VGPRs
typedef __attribute__((ext_vector_type(4))) short bf16x4;
typedef __attribute__((ext_vector_type(4))) float floatx4;
typedef unsigned short u16;

#define MFMA16(a,b,c) __builtin_amdgcn_mfma_f32_16x16x32_bf16((a),(b),(c),0,0,0)
#define ATT_SCALE 5.656854249492380f

__device__ __forceinline__ float bf2f(u16 u) { return __uint_as_float(((unsigned)u) << 16); }
__device__ __forceinline__ u16 f2bf(float f) {            // RNE
  unsigned u = __float_as_uint(f);
  u += 0x7fffu + ((u >> 16) & 1u);
  return (u16)(u >> 16);
}
// async global->LDS, 16B/lane; LDS dest must be wave-uniform base + lane*16 (m104)
__device__ __forceinline__ void gll16(const void* g, void* l) {
  __builtin_amdgcn_global_load_lds((const __attribute__((address_space(1))) void*)g,
                                   (__attribute__((address_space(3))) void*)l, 16, 0, 0);
}

// ---------------- fused preamble: dtype-detect + canonicalize all inputs ----------------
__global__ __launch_bounds__(256) void prep_k(
    const void* __restrict__ x, const void* __restrict__ qkv_w,
    const void* __restrict__ proj_w, const void* __restrict__ fc1_w,
    const void* __restrict__ fc2_w, const void* __restrict__ proj_b,
    const void* __restrict__ fc1_b, const void* __restrict__ fc2_b,
    const void* __restrict__ ln_g, const void* __restrict__ ln_b,
    u16* __restrict__ x_hi, u16* __restrict__ x_lo,
    u16* __restrict__ wq_hi, u16* __restrict__ wq_lo,
    u16* __restrict__ wt_proj, u16* __restrict__ wt_fc1, u16* __restrict__ wt_fc2,
    u16* __restrict__ b_proj, u16* __restrict__ b_fc1, u16* __restrict__ b_fc2,
    u16* __restrict__ g_ln, u16* __restrict__ bb_ln)
{
  // per-wave dtype sniff: fp32 backing -> ~46%/word |bf16-view|>1e3 or NaN.
  // P(miss over 64 words) ~ 4e-18.
  const int lane = threadIdx.x & 63;
  const float probe = bf2f(((const u16*)qkv_w)[lane]);
  const bool f32 = __ballot(!(fabsf(probe) < 1000.0f)) != 0ull;
  const int bid = blockIdx.x, tid = threadIdx.x;
  #define RD(p, i) (f32 ? ((const float*)(p))[i] : bf2f(((const u16*)(p))[i]))
  if (bid < 4096) {               // x -> hi+lo (1,048,576)
    const size_t i = (size_t)bid * 256 + tid;
    const float f = RD(x, i); const u16 h = f2bf(f);
    x_hi[i] = h; x_lo[i] = f2bf(f - bf2f(h));
  } else if (bid < 4864) {        // qkv_w^T -> hi+lo ([768][256])
    const int idx = (bid - 4096) * 256 + tid;
    const int n = idx >> 8, k = idx & 255;
    const float f = RD(qkv_w, (size_t)k * 768 + n); const u16 h = f2bf(f);
    wq_hi[idx] = h; wq_lo[idx] = f2bf(f - bf2f(h));
  } else if (bid < 5120) {        // proj_w^T ([256][256])
    const int idx = (bid - 4864) * 256 + tid;
    wt_proj[idx] = f2bf(RD(proj_w, (size_t)(idx & 255) * 256 + (idx >> 8)));
  } else if (bid < 6144) {        // fc1_w^T ([1024][256])
    const int idx = (bid - 5120) * 256 + tid;
    wt_fc1[idx] = f2bf(RD(fc1_w, (size_t)(idx & 255) * 1024 + (idx >> 8)));
  } else if (bid < 7168) {        // fc2_w^T ([256][1024])
    const int idx = (bid - 6144) * 256 + tid;
    wt_fc2[idx] = f2bf(RD(fc2_w, (size_t)(idx & 1023) * 256 + (idx >> 10)));
  } else {                        // biases + LN params (2048 elems, 8 blocks)
    const int j = (bid - 7168) * 256 + tid;
    if (j < 256)       b_proj[j]        = f2bf(RD(proj_b, j));
    else if (j < 1280) b_fc1[j - 256]   = f2bf(RD(fc1_b, j - 256));
    else if (j < 1536) b_fc2[j - 1280]  = f2bf(RD(fc2_b, j - 1280));
    else if (j < 1792) g_ln[j - 1536]   = f2bf(RD(ln_g, j - 1536));
    else               bb_ln[j - 1792]  = f2bf(RD(ln_b, j - 1792));
  }
  #undef RD
}

// ---------------- GEMM: C[M,Nn] = A[M,K] * Bt[Nn,K]^T  (bf16, fp32 accum) -----------
// EPI: 0 fp32 out, 1 bf16 out, 2 qkv split (q hi/lo, k hi/lo, vt transposed).
// SPLIT: 3-term hi/lo MFMA; skipped at runtime for V cols (n0>=512, V is bf16 anyway).
template<int TW, int EPI, bool BIAS, bool RES, bool SPLIT>
__global__ __launch_bounds__(256) void gemm_k(
    const u16* __restrict__ A, const u16* __restrict__ Bt,
    const u16* __restrict__ A2, const u16* __restrict__ B2,
    const u16* __restrict__ bias, const u16* __restrict__ res,
    void* __restrict__ out0, u16* __restrict__ aux1, u16* __restrict__ aux2,
    u16* __restrict__ aux3, u16* __restrict__ aux4,
    int M, int Nn, int K)
{
  constexpr int BT = TW * 32;
  __shared__ __align__(16) short As[BT][40];
  __shared__ __align__(16) short Bs[BT][40];
  __shared__ __align__(16) short As2[SPLIT ? BT : 1][40];
  __shared__ __align__(16) short Bs2[SPLIT ? BT : 1][40];
  const int tid = threadIdx.x;
  const int m0 = blockIdx.y * BT, n0 = blockIdx.x * BT;
  const bool sp = SPLIT && (n0 < 512);   // V cols need no hi/lo accuracy
  const int wid = tid >> 6, lane = tid & 63;
  const int wm = (wid >> 1) * (TW * 16), wn = (wid & 1) * (TW * 16);
  const int lm = lane & 15, quad = lane >> 4;

  floatx4 zero = {0.f, 0.f, 0.f, 0.f};
  floatx4 acc[TW][TW];
#pragma unroll
  for (int i = 0; i < TW; ++i)
#pragma unroll
    for (int j = 0; j < TW; ++j) acc[i][j] = zero;

  for (int k0 = 0; k0 < K; k0 += 32) {
#pragma unroll
    for (int c = 0; c < TW / 2; ++c) {
      int cid = tid * (TW / 2) + c;
      int row = cid >> 2, off = (cid & 3) * 8;
      const size_t ga = (size_t)(m0 + row) * K + k0 + off;
      const size_t gb = (size_t)(n0 + row) * K + k0 + off;
      *(short8*)&As[row][off] = *(const short8*)&A[ga];
      *(short8*)&Bs[row][off] = *(const short8*)&Bt[gb];
      if (sp) {
        *(short8*)&As2[row][off] = *(const short8*)&A2[ga];
        *(short8*)&Bs2[row][off] = *(const short8*)&B2[gb];
      }
    }
    __syncthreads();
    short8 fa[TW], fb[TW], fa2[TW], fb2[TW];
#pragma unroll
    for (int t = 0; t < TW; ++t) {
      fa[t] = *(const short8*)&As[wm + t * 16 + lm][quad * 8];
      fb[t] = *(const short8*)&Bs[wn + t * 16 + lm][quad * 8];
      if (sp) {
        fa2[t] = *(const short8*)&As2[wm + t * 16 + lm][quad * 8];
        fb2[t] = *(const short8*)&Bs2[wn + t * 16 + lm][quad * 8];
      }
    }
#pragma unroll
    for (int i = 0; i < TW; ++i)
#pragma unroll
      for (int j = 0; j < TW; ++j) {
        if (sp) {
          acc[i][j] = MFMA16(fa[i], fb2[j], acc[i][j]);
          acc[i][j] = MFMA16(fa2[i], fb[j], acc[i][j]);
        }
        acc[i][j] = MFMA16(fa[i], fb[j], acc[i][j]);
      }
    __syncthreads();
  }

  // epilogue: C/D layout col=lane&15, row=quad*4+reg
#pragma unroll
  for (int i = 0; i < TW; ++i) {
    const int rowb = m0 + wm + i * 16 + quad * 4;
#pragma unroll
    for (int j = 0; j < TW; ++j) {
      const int col = n0 + wn + j * 16 + lm;
      const float bv = BIAS ? bf2f(bias[col]) : 0.f;
#pragma unroll
      for (int r = 0; r < 4; ++r) {
        const int row = rowb + r;
        float v = acc[i][j][r] + bv;
        const size_t o = (size_t)row * Nn + col;
        if (RES) v += bf2f(res[o]);
        if (EPI == 0) {
          ((float*)out0)[o] = v;
        } else if (EPI == 1) {
          ((u16*)out0)[o] = f2bf(v);
        } else {
          u16 hi = f2bf(v);
          u16 lo = f2bf(v - bf2f(hi));
          if (col < 256) {
            const size_t oq = (size_t)row * 256 + col;
            aux1[oq] = hi; aux2[oq] = lo;       // Q
          } else if (col < 512) {
            const size_t ok = (size_t)row * 256 + (col - 256);
            aux3[ok] = hi; aux4[ok] = lo;       // K
          } else {                              // V -> per-head transposed [bh][32][2048]
            int d = col & 31, hh = (col >> 5) & 7;
            int bb = row >> 11, n = row & 2047;
            ((u16*)out0)[(size_t)((bb * 8 + hh) * 32 + d) * 2048 + n] = hi;
          }
        }
      }
    }
  }
}

// ---------------- flash attention v2: 2 waves/block, 32 q-rows, dbuf async staging ----
__global__ __launch_bounds__(128) void attn_k(
    const u16* __restrict__ qhi, const u16* __restrict__ qlo,
    const u16* __restrict__ khi, const u16* __restrict__ klo,
    const u16* __restrict__ vt, u16* __restrict__ attn)
{
  __shared__ __align__(16) u16 Khi[2][64][32];   // [buf][key][d] granule-swizzled
  __shared__ __align__(16) u16 Klo[2][64][32];
  __shared__ __align__(16) u16 Vs [2][32][64];   // [buf][d][key] granule-swizzled
  __shared__ __align__(16) u16 Pst[2][64][20];   // [wave][key][qrow+pad]
  const int tid = threadIdx.x, wid = tid >> 6, lane = tid & 63;
  const int lm = lane & 15, quad = lane >> 4;
  const int qblk = blockIdx.x & 63, bh = blockIdx.x >> 6;   // consecutive bids share head
  const int b = bh >> 3, h = bh & 7;
  const int q0 = qblk * 32 + wid * 16;
  const size_t tb = (size_t)b * 2048;

  short8 qh, ql;
  { size_t off = (tb + q0 + lm) * 256 + h * 32 + quad * 8;  // Q A-frag, persistent
    qh = *(const short8*)&qhi[off];
    ql = *(const short8*)&qlo[off]; }

  // staging: 2 slots/thread/buffer; slot s holds 16B at LDS linear s*16 (m104 rule).
  // K slot s -> key r=s>>2, phys granule p=s&3, logical g = p ^ ((r+(r>>2))&3).
  const int s0 = tid, s1 = tid + 128;
  const int kr0 = s0 >> 2, kg0 = (s0 & 3) ^ ((kr0 + (kr0 >> 2)) & 3);
  const int kr1 = s1 >> 2, kg1 = (s1 & 3) ^ ((kr1 + (kr1 >> 2)) & 3);
  const size_t kb0 = (tb + kr0) * 256 + h * 32 + kg0 * 8;
  const size_t kb1 = (tb + kr1) * 256 + h * 32 + kg1 * 8;
  // V slot s -> d=s>>3, phys granule p=s&7, logical g = p ^ (d&7).
  const int vd0 = s0 >> 3, vg0 = (s0 & 7) ^ (vd0 & 7);
  const int vd1 = s1 >> 3, vg1 = (s1 & 7) ^ (vd1 & 7);
  const size_t vb0 = (size_t)(bh * 32 + vd0) * 2048 + vg0 * 8;
  const size_t vb1 = (size_t)(bh * 32 + vd1) * 2048 + vg1 * 8;

  // prologue: stage tile 0 -> buf 0
  gll16(khi + kb0, (u16*)Khi + s0 * 8);
  gll16(khi + kb1, (u16*)Khi + s1 * 8);
  gll16(klo + kb0, (u16*)Klo + s0 * 8);
  gll16(klo + kb1, (u16*)Klo + s1 * 8);
  gll16(vt  + vb0, (u16*)Vs  + s0 * 8);
  gll16(vt  + vb1, (u16*)Vs  + s1 * 8);

  float mrun[4], lrun[4];
  floatx4 o0 = {0.f,0.f,0.f,0.f}, o1 = {0.f,0.f,0.f,0.f};
#pragma unroll
  for (int r = 0; r < 4; ++r) { mrun[r] = -1e30f; lrun[r] = 0.f; }
  short8 vONE;
#pragma unroll
  for (int j = 0; j < 8; ++j) vONE[j] = (short)0x3F80;      // bf16 1.0

  for (int kt = 0; kt < 32; ++kt) {
    const int buf = kt & 1;
    __syncthreads();   // vmcnt drain: tile kt resident; prev reads of buf^1 done
    if (kt < 31) {     // issue tile kt+1 -> buf^1; in flight across this compute phase
      const int nb = buf ^ 1;
      const size_t ko = (size_t)(kt + 1) * 64 * 256;
      const size_t vo = (size_t)(kt + 1) * 64;
      gll16(khi + kb0 + ko, (u16*)Khi + nb * 2048 + s0 * 8);
      gll16(khi + kb1 + ko, (u16*)Khi + nb * 2048 + s1 * 8);
      gll16(klo + kb0 + ko, (u16*)Klo + nb * 2048 + s0 * 8);
      gll16(klo + kb1 + ko, (u16*)Klo + nb * 2048 + s1 * 8);
      gll16(vt  + vb0 + vo, (u16*)Vs  + nb * 2048 + s0 * 8);
      gll16(vt  + vb1 + vo, (u16*)Vs  + nb * 2048 + s1 * 8);
    }

    // S = (qh*kh + qh*kl + ql*kh) * SCALE
    floatx4 s[4];
#pragma unroll
    for (int kf = 0; kf < 4; ++kf) {
      const int row = kf * 16 + lm;
      const int p = (quad ^ ((row + (row >> 2)) & 3)) * 8;
      short8 kh = *(const short8*)&Khi[buf][row][p];
      short8 kl = *(const short8*)&Klo[buf][row][p];
      floatx4 z = {0.f,0.f,0.f,0.f};
      z = MFMA16(qh, kl, z);
      z = MFMA16(ql, kh, z);
      z = MFMA16(qh, kh, z);
      s[kf] = z * ATT_SCALE;
    }
    // online softmax max (16-lane quad reduction)
    float rmax[4];
#pragma unroll
    for (int r = 0; r < 4; ++r)
      rmax[r] = fmaxf(fmaxf(s[0][r], s[1][r]), fmaxf(s[2][r], s[3][r]));
#pragma unroll
    for (int r = 0; r < 4; ++r)
#pragma unroll
      for (int d = 1; d < 16; d <<= 1)
        rmax[r] = fmaxf(rmax[r], __shfl_xor(rmax[r], d, 16));
    float alpha[4];
#pragma unroll
    for (int r = 0; r < 4; ++r) {
      const float mn = fmaxf(mrun[r], rmax[r]);
      alpha[r] = __expf(mrun[r] - mn);
      mrun[r] = mn;
    }
    // P = exp(S - m) -> Pst[key][qrow] (b64 per kf, conflict-light)
#pragma unroll
    for (int kf = 0; kf < 4; ++kf) {
      bf16x4 pk;
#pragma unroll
      for (int r = 0; r < 4; ++r) pk[r] = (short)f2bf(__expf(s[kf][r] - mrun[r]));
      *(bf16x4*)&Pst[wid][kf * 16 + lm][quad * 4] = pk;
    }
    // A-frag read: P[m=lm][k=quad*8+j] = Pst[key][lm]  (wave-private, no barrier)
    short8 pf0, pf1;
#pragma unroll
    for (int j = 0; j < 8; ++j) {
      pf0[j] = (short)Pst[wid][quad * 8 + j][lm];
      pf1[j] = (short)Pst[wid][32 + quad * 8 + j][lm];
    }
    // V B-frags (swizzled granules)
    const int vs = lm & 7;
    short8 v00 = *(const short8*)&Vs[buf][lm]     [((0 + quad) ^ vs) * 8];
    short8 v10 = *(const short8*)&Vs[buf][lm]     [((4 + quad) ^ vs) * 8];
    short8 v01 = *(const short8*)&Vs[buf][16 + lm][((0 + quad) ^ vs) * 8];
    short8 v11 = *(const short8*)&Vs[buf][16 + lm][((4 + quad) ^ vs) * 8];
    // rescale + accumulate; l via ones-MFMA (C[m][n] = sum_k P[m][k])
#pragma unroll
    for (int r = 0; r < 4; ++r) { o0[r] *= alpha[r]; o1[r] *= alpha[r]; }
    o0 = MFMA16(pf0, v00, o0);
    o0 = MFMA16(pf1, v10, o0);
    o1 = MFMA16(pf0, v01, o1);
    o1 = MFMA16(pf1, v11, o1);
    floatx4 z2 = {0.f,0.f,0.f,0.f};
    z2 = MFMA16(pf0, vONE, z2);
    z2 = MFMA16(pf1, vONE, z2);
#pragma unroll
    for (int r = 0; r < 4; ++r) lrun[r] = lrun[r] * alpha[r] + z2[r];
  }
#pragma unroll
  for (int r = 0; r < 4; ++r) {
    const float inv = 1.0f / lrun[r];
    const size_t row = tb + q0 + quad * 4 + r;
    attn[row * 256 + h * 32 + lm]      = f2bf(o0[r] * inv);
    attn[row * 256 + h * 32 + 16 + lm] = f2bf(o1[r] * inv);
  }
}

// ---------------- residual add + LayerNorm: net = LN(projf + x) ----------------
__global__ __launch_bounds__(256) void ln_k(const float* __restrict__ pf,
                                            const u16* __restrict__ xh,
                                            const u16* __restrict__ xl,
                                            const u16* __restrict__ g,
                                            const u16* __restrict__ bta,
                                            u16* __restrict__ net)
{
  const int t = blockIdx.x, c = threadIdx.x;
  const size_t o = (size_t)t * 256 + c;
  float v = pf[o] + bf2f(xh[o]) + bf2f(xl[o]);
  float s = v, s2 = v * v;
#pragma unroll
  for (int d = 1; d < 64; d <<= 1) { s += __shfl_xor(s, d); s2 += __shfl_xor(s2, d); }
  __shared__ float ss[4], ss2[4];
  const int w = c >> 6;
  if ((c & 63) == 0) { ss[w] = s; ss2[w] = s2; }
  __syncthreads();
  s = ss[0] + ss[1] + ss[2] + ss[3];
  s2 = ss2[0] + ss2[1] + ss2[2] + ss2[3];
  const float mu = s * (1.f / 256.f);
  const float var = s2 * (1.f / 256.f) - mu * mu;
  const float is = rsqrtf(var + 1e-5f);
  net[o] = f2bf((v - mu) * is * bf2f(g[c]) + bf2f(bta[c]));
}

extern "C" void kernel_launch(void* const* d_in, const int* in_sizes, int n_in,
                              void* d_out, int out_size, void* d_ws, size_t ws_size,
                              hipStream_t stream) {
  const void* x      = d_in[0];
  const void* qkv_w  = d_in[1];
  const void* proj_w = d_in[2];
  const void* proj_b = d_in[3];
  const void* fc1_w  = d_in[4];
  const void* fc1_b  = d_in[5];
  const void* fc2_w  = d_in[6];
  const void* fc2_b  = d_in[7];
  const void* ln_g   = d_in[8];
  const void* ln_b   = d_in[9];

  char* ws = (char*)d_ws;
  u16* b_proj  = (u16*)(ws + 4096);
  u16* b_fc1   = (u16*)(ws + 8192);
  u16* b_fc2   = (u16*)(ws + 12288);
  u16* g_ln    = (u16*)(ws + 16384);
  u16* bb_ln   = (u16*)(ws + 20480);
  u16* wq_hi   = (u16*)(ws + 131072);    // [768][256]
  u16* wq_lo   = (u16*)(ws + 524288);
  u16* wt_proj = (u16*)(ws + 917504);    // [256][256]
  u16* wt_fc1  = (u16*)(ws + 1048576);   // [1024][256]
  u16* wt_fc2  = (u16*)(ws + 1572864);   // [256][1024]
  u16* x_hi    = (u16*)(ws + 2097152);   // [4096][256]
  u16* x_lo    = (u16*)(ws + 4194304);
  u16* q_hi    = (u16*)(ws + 6291456);
  u16* q_lo    = (u16*)(ws + 8388608);
  u16* k_hi    = (u16*)(ws + 10485760);
  u16* k_lo    = (u16*)(ws + 12582912);
  u16* vt      = (u16*)(ws + 14680064);  // [16 bh][32 d][2048 n]; end 16MB
  u16* attn    = (u16*)d_out;            // first 2MB of d_out = attn scratch (bf16)
  float* projf = (float*)(ws + 6291456); // 4MB fp32 over dead Q
  u16* net     = (u16*)(ws + 14680064);  // 2MB over dead vt
  u16* hbuf    = (u16*)(ws + 2097152);   // 8MB over dead x/projf

  prep_k<<<7176, 256, 0, stream>>>(x, qkv_w, proj_w, fc1_w, fc2_w,
                                   proj_b, fc1_b, fc2_b, ln_g, ln_b,
                                   x_hi, x_lo, wq_hi, wq_lo, wt_proj, wt_fc1, wt_fc2,
                                   b_proj, b_fc1, b_fc2, g_ln, bb_ln);

  // qkv = x @ qkv_w, 3-term hi/lo (V cols plain) -> q hi/lo, k hi/lo, vt
  gemm_k<4, 2, false, false, true><<<dim3(6, 32), 256, 0, stream>>>(
      x_hi, wq_hi, x_lo, wq_lo, nullptr, nullptr, vt, q_hi, q_lo, k_hi, k_lo, 4096, 768, 256);
  attn_k<<<1024, 128, 0, stream>>>(q_hi, q_lo, k_hi, k_lo, vt, attn);
  // proj (+bias) -> fp32
  gemm_k<2, 0, true, false, false><<<dim3(4, 64), 256, 0, stream>>>(
      attn, wt_proj, nullptr, nullptr, b_proj, nullptr, projf,
      nullptr, nullptr, nullptr, nullptr, 4096, 256, 256);
  ln_k<<<4096, 256, 0, stream>>>(projf, x_hi, x_lo, g_ln, bb_ln, net);
  // fc1 (+bias)
  gemm_k<4, 1, true, false, false><<<dim3(8, 32), 256, 0, stream>>>(
      net, wt_fc1, nullptr, nullptr, b_fc1, nullptr, hbuf,
      nullptr, nullptr, nullptr, nullptr, 4096, 1024, 256);
  // fc2 (+bias +shortcut) -> d_out fp32
  gemm_k<2, 0, true, true, false><<<dim3(4, 64), 256, 0, stream>>>(
      hbuf, wt_fc2, nullptr, nullptr, b_fc2, net, d_out,
      nullptr, nullptr, nullptr, nullptr, 4096, 256, 1024);
}

// Round 9
// 192.221 us; speedup vs baseline: 3.4115x; 1.0571x over previous
//
#include <hip/hip_runtime.h>

// B=2,N=2048,D=256,H=8,HD=32,DFF=1024. SCALE MULTIPLIES by sqrt(32). No MLP
// activation. Post-norm. Inputs fp32 (auto-detected), output fp32.
// Verified R5-R8: absmax 0.031 vs threshold 0.134.
//
// R9: attn_k v3 — compute S^T = K*Q^T (operand swap, same loads). The S^T
// C-layout (qrow=lm, keys kf*16+quad*4+r) IS the B-operand layout of
// mfma_f32_16x16x16 (k=quad*4+j, n=lm): P^T feeds the PV MFMA straight from
// registers. Kills: 16 ds_write + 16 conflicted ds_read (P transform),
// 14 of 16 shuffle-reduction ops, 20 muls (exp2 folding), ones-MFMA.
// PV: O^T = V^T * P^T via 8 x16 MFMAs; V^T A-frags = b64 reads of the
// granule-swizzled Vs (at-floor banking). Epilogue writes O^T scalar (1x cost).

typedef __attribute__((ext_vector_type(8))) short short8;   // 8 bf16 = 4 VGPRs
typedef __attribute__((ext_vector_type(4))) short bf16x4;   // 4 bf16 = 2 VGPRs
typedef __attribute__((ext_vector_type(4))) float floatx4;
typedef unsigned short u16;

#define MFMA32(a,b,c) __builtin_amdgcn_mfma_f32_16x16x32_bf16((a),(b),(c),0,0,0)
#if __has_builtin(__builtin_amdgcn_mfma_f32_16x16x16_bf16)
#define MFMAPV(a,b,c) __builtin_amdgcn_mfma_f32_16x16x16_bf16((a),(b),(c),0,0,0)
#else
#define MFMAPV(a,b,c) __builtin_amdgcn_mfma_f32_16x16x16bf16_1k((a),(b),(c),0,0,0)
#endif
#define ATT_SCALE 5.656854249492380f

__device__ __forceinline__ float bf2f(u16 u) { return __uint_as_float(((unsigned)u) << 16); }
__device__ __forceinline__ u16 f2bf(float f) {            // RNE
  unsigned u = __float_as_uint(f);
  u += 0x7fffu + ((u >> 16) & 1u);
  return (u16)(u >> 16);
}
// async global->LDS, 16B/lane; LDS dest must be wave-uniform base + lane*16 (m104)
__device__ __forceinline__ void gll16(const void* g, void* l) {
  __builtin_amdgcn_global_load_lds((const __attribute__((address_space(1))) void*)g,
                                   (__attribute__((address_space(3))) void*)l, 16, 0, 0);
}

// ---------------- fused preamble: dtype-detect + canonicalize all inputs ----------------
__global__ __launch_bounds__(256) void prep_k(
    const void* __restrict__ x, const void* __restrict__ qkv_w,
    const void* __restrict__ proj_w, const void* __restrict__ fc1_w,
    const void* __restrict__ fc2_w, const void* __restrict__ proj_b,
    const void* __restrict__ fc1_b, const void* __restrict__ fc2_b,
    const void* __restrict__ ln_g, const void* __restrict__ ln_b,
    u16* __restrict__ x_hi, u16* __restrict__ x_lo,
    u16* __restrict__ wq_hi, u16* __restrict__ wq_lo,
    u16* __restrict__ wt_proj, u16* __restrict__ wt_fc1, u16* __restrict__ wt_fc2,
    u16* __restrict__ b_proj, u16* __restrict__ b_fc1, u16* __restrict__ b_fc2,
    u16* __restrict__ g_ln, u16* __restrict__ bb_ln)
{
  const int lane = threadIdx.x & 63;
  const float probe = bf2f(((const u16*)qkv_w)[lane]);
  const bool f32 = __ballot(!(fabsf(probe) < 1000.0f)) != 0ull;
  const int bid = blockIdx.x, tid = threadIdx.x;
  #define RD(p, i) (f32 ? ((const float*)(p))[i] : bf2f(((const u16*)(p))[i]))
  if (bid < 4096) {               // x -> hi+lo
    const size_t i = (size_t)bid * 256 + tid;
    const float f = RD(x, i); const u16 h = f2bf(f);
    x_hi[i] = h; x_lo[i] = f2bf(f - bf2f(h));
  } else if (bid < 4864) {        // qkv_w^T -> hi+lo ([768][256])
    const int idx = (bid - 4096) * 256 + tid;
    const int n = idx >> 8, k = idx & 255;
    const float f = RD(qkv_w, (size_t)k * 768 + n); const u16 h = f2bf(f);
    wq_hi[idx] = h; wq_lo[idx] = f2bf(f - bf2f(h));
  } else if (bid < 5120) {        // proj_w^T ([256][256])
    const int idx = (bid - 4864) * 256 + tid;
    wt_proj[idx] = f2bf(RD(proj_w, (size_t)(idx & 255) * 256 + (idx >> 8)));
  } else if (bid < 6144) {        // fc1_w^T ([1024][256])
    const int idx = (bid - 5120) * 256 + tid;
    wt_fc1[idx] = f2bf(RD(fc1_w, (size_t)(idx & 255) * 1024 + (idx >> 8)));
  } else if (bid < 7168) {        // fc2_w^T ([256][1024])
    const int idx = (bid - 6144) * 256 + tid;
    wt_fc2[idx] = f2bf(RD(fc2_w, (size_t)(idx & 1023) * 256 + (idx >> 10)));
  } else {                        // biases + LN params
    const int j = (bid - 7168) * 256 + tid;
    if (j < 256)       b_proj[j]        = f2bf(RD(proj_b, j));
    else if (j < 1280) b_fc1[j - 256]   = f2bf(RD(fc1_b, j - 256));
    else if (j < 1536) b_fc2[j - 1280]  = f2bf(RD(fc2_b, j - 1280));
    else if (j < 1792) g_ln[j - 1536]   = f2bf(RD(ln_g, j - 1536));
    else               bb_ln[j - 1792]  = f2bf(RD(ln_b, j - 1792));
  }
  #undef RD
}

// ---------------- GEMM: C[M,Nn] = A[M,K] * Bt[Nn,K]^T  (bf16, fp32 accum) -----------
template<int TW, int EPI, bool BIAS, bool RES, bool SPLIT>
__global__ __launch_bounds__(256) void gemm_k(
    const u16* __restrict__ A, const u16* __restrict__ Bt,
    const u16* __restrict__ A2, const u16* __restrict__ B2,
    const u16* __restrict__ bias, const u16* __restrict__ res,
    void* __restrict__ out0, u16* __restrict__ aux1, u16* __restrict__ aux2,
    u16* __restrict__ aux3, u16* __restrict__ aux4,
    int M, int Nn, int K)
{
  constexpr int BT = TW * 32;
  __shared__ __align__(16) short As[BT][40];
  __shared__ __align__(16) short Bs[BT][40];
  __shared__ __align__(16) short As2[SPLIT ? BT : 1][40];
  __shared__ __align__(16) short Bs2[SPLIT ? BT : 1][40];
  const int tid = threadIdx.x;
  const int m0 = blockIdx.y * BT, n0 = blockIdx.x * BT;
  const bool sp = SPLIT && (n0 < 512);
  const int wid = tid >> 6, lane = tid & 63;
  const int wm = (wid >> 1) * (TW * 16), wn = (wid & 1) * (TW * 16);
  const int lm = lane & 15, quad = lane >> 4;

  floatx4 zero = {0.f, 0.f, 0.f, 0.f};
  floatx4 acc[TW][TW];
#pragma unroll
  for (int i = 0; i < TW; ++i)
#pragma unroll
    for (int j = 0; j < TW; ++j) acc[i][j] = zero;

  for (int k0 = 0; k0 < K; k0 += 32) {
#pragma unroll
    for (int c = 0; c < TW / 2; ++c) {
      int cid = tid * (TW / 2) + c;
      int row = cid >> 2, off = (cid & 3) * 8;
      const size_t ga = (size_t)(m0 + row) * K + k0 + off;
      const size_t gb = (size_t)(n0 + row) * K + k0 + off;
      *(short8*)&As[row][off] = *(const short8*)&A[ga];
      *(short8*)&Bs[row][off] = *(const short8*)&Bt[gb];
      if (sp) {
        *(short8*)&As2[row][off] = *(const short8*)&A2[ga];
        *(short8*)&Bs2[row][off] = *(const short8*)&B2[gb];
      }
    }
    __syncthreads();
    short8 fa[TW], fb[TW], fa2[TW], fb2[TW];
#pragma unroll
    for (int t = 0; t < TW; ++t) {
      fa[t] = *(const short8*)&As[wm + t * 16 + lm][quad * 8];
      fb[t] = *(const short8*)&Bs[wn + t * 16 + lm][quad * 8];
      if (sp) {
        fa2[t] = *(const short8*)&As2[wm + t * 16 + lm][quad * 8];
        fb2[t] = *(const short8*)&Bs2[wn + t * 16 + lm][quad * 8];
      }
    }
#pragma unroll
    for (int i = 0; i < TW; ++i)
#pragma unroll
      for (int j = 0; j < TW; ++j) {
        if (sp) {
          acc[i][j] = MFMA32(fa[i], fb2[j], acc[i][j]);
          acc[i][j] = MFMA32(fa2[i], fb[j], acc[i][j]);
        }
        acc[i][j] = MFMA32(fa[i], fb[j], acc[i][j]);
      }
    __syncthreads();
  }

#pragma unroll
  for (int i = 0; i < TW; ++i) {
    const int rowb = m0 + wm + i * 16 + quad * 4;
#pragma unroll
    for (int j = 0; j < TW; ++j) {
      const int col = n0 + wn + j * 16 + lm;
      const float bv = BIAS ? bf2f(bias[col]) : 0.f;
#pragma unroll
      for (int r = 0; r < 4; ++r) {
        const int row = rowb + r;
        float v = acc[i][j][r] + bv;
        const size_t o = (size_t)row * Nn + col;
        if (RES) v += bf2f(res[o]);
        if (EPI == 0) {
          ((float*)out0)[o] = v;
        } else if (EPI == 1) {
          ((u16*)out0)[o] = f2bf(v);
        } else {
          u16 hi = f2bf(v);
          u16 lo = f2bf(v - bf2f(hi));
          if (col < 256) {
            const size_t oq = (size_t)row * 256 + col;
            aux1[oq] = hi; aux2[oq] = lo;       // Q
          } else if (col < 512) {
            const size_t ok = (size_t)row * 256 + (col - 256);
            aux3[ok] = hi; aux4[ok] = lo;       // K
          } else {                              // V -> per-head transposed [bh][32][2048]
            int d = col & 31, hh = (col >> 5) & 7;
            int bb = row >> 11, n = row & 2047;
            ((u16*)out0)[(size_t)((bb * 8 + hh) * 32 + d) * 2048 + n] = hi;
          }
        }
      }
    }
  }
}

// ---------------- flash attention v3: S^T form, register-direct P, 4 waves/block ----
__global__ __launch_bounds__(256) void attn_k(
    const u16* __restrict__ qhi, const u16* __restrict__ qlo,
    const u16* __restrict__ khi, const u16* __restrict__ klo,
    const u16* __restrict__ vt, u16* __restrict__ attn)
{
  __shared__ __align__(16) u16 Khi[2][64][32];   // [buf][key][d], unswizzled
  __shared__ __align__(16) u16 Klo[2][64][32];
  __shared__ __align__(16) u16 Vs [2][32][64];   // [buf][d][key], key-octet ^ (d&7)
  const int tid = threadIdx.x, wid = tid >> 6, lane = tid & 63;
  const int lm = lane & 15, quad = lane >> 4;
  const int qblk = blockIdx.x & 31, bh = blockIdx.x >> 5;   // 32 qblocks x 16 (b,h)
  const int b = bh >> 3, h = bh & 7;
  const int q0 = qblk * 64 + wid * 16;
  const size_t tb = (size_t)b * 2048;
  const float CL = (float)(5.656854249492380 * 1.4426950408889634);  // SCALE*log2(e)

  short8 qh, ql;   // Q^T B-frag (k=d=quad*8+j, n=qrow=lm) — same bytes as A-frag of Q
  { size_t off = (tb + q0 + lm) * 256 + h * 32 + quad * 8;
    qh = *(const short8*)&qhi[off];
    ql = *(const short8*)&qlo[off]; }

  // staging: 256 threads, 1 granule (16B) each per buffer per tile.
  const int kkey = tid >> 2, kg = tid & 3;                  // K: [key][d-octet]
  const size_t kb = (tb + kkey) * 256 + h * 32 + kg * 8;
  const int vd = tid >> 3, vp = tid & 7, vk8 = vp ^ (vd & 7);  // V: swizzled key-octet
  const size_t vb = (size_t)(bh * 32 + vd) * 2048 + vk8 * 8;

  gll16(khi + kb, (u16*)Khi + tid * 8);
  gll16(klo + kb, (u16*)Klo + tid * 8);
  gll16(vt  + vb, (u16*)Vs  + tid * 8);

  float mrun = -1e30f, lrun = 0.f;
  floatx4 o0 = {0.f,0.f,0.f,0.f}, o1 = {0.f,0.f,0.f,0.f};

  for (int kt = 0; kt < 32; ++kt) {
    const int buf = kt & 1;
    __syncthreads();             // implicit vmcnt(0) drain: tile kt resident
    if (kt < 31) {               // stage kt+1 -> buf^1, in flight across compute
      const int nb = (buf ^ 1) * 2048;
      const size_t ko = (size_t)(kt + 1) * 16384;   // 64 keys * 256
      const size_t vo = (size_t)(kt + 1) * 64;
      gll16(khi + kb + ko, (u16*)Khi + nb + tid * 8);
      gll16(klo + kb + ko, (u16*)Klo + nb + tid * 8);
      gll16(vt  + vb + vo, (u16*)Vs  + nb + tid * 8);
    }

    // S^T tile kf: A = K (m=key=kf*16+lm, k=d=quad*8+j), B = Q^T. Raw z (unscaled).
    floatx4 z[4];
#pragma unroll
    for (int kf = 0; kf < 4; ++kf) {
      short8 khf = *(const short8*)&Khi[buf][kf * 16 + lm][quad * 8];
      short8 klf = *(const short8*)&Klo[buf][kf * 16 + lm][quad * 8];
      floatx4 zz = {0.f,0.f,0.f,0.f};
      zz = MFMA32(khf, ql, zz);
      zz = MFMA32(klf, qh, zz);
      zz = MFMA32(khf, qh, zz);
      z[kf] = zz;
    }
    // per-qrow max: in-lane 16 + 2 cross-quad shuffles (lanes with same lm)
    float zm = fmaxf(fmaxf(fmaxf(z[0][0], z[0][1]), fmaxf(z[0][2], z[0][3])),
               fmaxf(fmaxf(z[1][0], z[1][1]), fmaxf(z[1][2], z[1][3])));
    zm = fmaxf(zm, fmaxf(fmaxf(fmaxf(z[2][0], z[2][1]), fmaxf(z[2][2], z[2][3])),
                   fmaxf(fmaxf(z[3][0], z[3][1]), fmaxf(z[3][2], z[3][3]))));
    zm = fmaxf(zm, __shfl_xor(zm, 16));
    zm = fmaxf(zm, __shfl_xor(zm, 32));
    const float mn = fmaxf(mrun, zm);
    const float alpha = exp2f((mrun - mn) * CL);
    const float mc = mn * CL;
    mrun = mn;
    // P = 2^(z*CL - mc); sum in-lane + 2 shuffles; pack to x16 B-frags
    float ls = 0.f;
    bf16x4 pb[4];
#pragma unroll
    for (int kf = 0; kf < 4; ++kf)
#pragma unroll
      for (int r = 0; r < 4; ++r) {
        const float p = exp2f(__builtin_fmaf(z[kf][r], CL, -mc));
        ls += p;
        pb[kf][r] = (short)f2bf(p);
      }
    ls += __shfl_xor(ls, 16);
    ls += __shfl_xor(ls, 32);
    lrun = lrun * alpha + ls;
#pragma unroll
    for (int r = 0; r < 4; ++r) { o0[r] *= alpha; o1[r] *= alpha; }
    // O^T += V^T * P^T : 2 d-chunks x 4 kf, x16 MFMAs; P^T straight from regs
    const u16* vbase = (const u16*)Vs + buf * 2048;
#pragma unroll
    for (int kf = 0; kf < 4; ++kf) {
      const int k8 = 2 * kf + (quad >> 1);
      const int d0 = lm, d1 = 16 + lm;
      bf16x4 vf0 = *(const bf16x4*)(vbase + (d0 * 8 + (k8 ^ (d0 & 7))) * 8 + (quad & 1) * 4);
      bf16x4 vf1 = *(const bf16x4*)(vbase + (d1 * 8 + (k8 ^ (d1 & 7))) * 8 + (quad & 1) * 4);
      o0 = MFMAPV(vf0, pb[kf], o0);
      o1 = MFMAPV(vf1, pb[kf], o1);
    }
  }
  // epilogue: O^T C-layout: qrow=lm, d = chunk*16 + quad*4 + r
  const float inv = 1.0f / lrun;
  const size_t rowo = (tb + q0 + lm) * 256 + h * 32;
#pragma unroll
  for (int r = 0; r < 4; ++r) {
    attn[rowo + quad * 4 + r]      = f2bf(o0[r] * inv);
    attn[rowo + 16 + quad * 4 + r] = f2bf(o1[r] * inv);
  }
}

// ---------------- residual add + LayerNorm: net = LN(projf + x) ----------------
__global__ __launch_bounds__(256) void ln_k(const float* __restrict__ pf,
                                            const u16* __restrict__ xh,
                                            const u16* __restrict__ xl,
                                            const u16* __restrict__ g,
                                            const u16* __restrict__ bta,
                                            u16* __restrict__ net)
{
  const int t = blockIdx.x, c = threadIdx.x;
  const size_t o = (size_t)t * 256 + c;
  float v = pf[o] + bf2f(xh[o]) + bf2f(xl[o]);
  float s = v, s2 = v * v;
#pragma unroll
  for (int d = 1; d < 64; d <<= 1) { s += __shfl_xor(s, d); s2 += __shfl_xor(s2, d); }
  __shared__ float ss[4], ss2[4];
  const int w = c >> 6;
  if ((c & 63) == 0) { ss[w] = s; ss2[w] = s2; }
  __syncthreads();
  s = ss[0] + ss[1] + ss[2] + ss[3];
  s2 = ss2[0] + ss2[1] + ss2[2] + ss2[3];
  const float mu = s * (1.f / 256.f);
  const float var = s2 * (1.f / 256.f) - mu * mu;
  const float is = rsqrtf(var + 1e-5f);
  net[o] = f2bf((v - mu) * is * bf2f(g[c]) + bf2f(bta[c]));
}

extern "C" void kernel_launch(void* const* d_in, const int* in_sizes, int n_in,
                              void* d_out, int out_size, void* d_ws, size_t ws_size,
                              hipStream_t stream) {
  const void* x      = d_in[0];
  const void* qkv_w  = d_in[1];
  const void* proj_w = d_in[2];
  const void* proj_b = d_in[3];
  const void* fc1_w  = d_in[4];
  const void* fc1_b  = d_in[5];
  const void* fc2_w  = d_in[6];
  const void* fc2_b  = d_in[7];
  const void* ln_g   = d_in[8];
  const void* ln_b   = d_in[9];

  char* ws = (char*)d_ws;
  u16* b_proj  = (u16*)(ws + 4096);
  u16* b_fc1   = (u16*)(ws + 8192);
  u16* b_fc2   = (u16*)(ws + 12288);
  u16* g_ln    = (u16*)(ws + 16384);
  u16* bb_ln   = (u16*)(ws + 20480);
  u16* wq_hi   = (u16*)(ws + 131072);    // [768][256]
  u16* wq_lo   = (u16*)(ws + 524288);
  u16* wt_proj = (u16*)(ws + 917504);    // [256][256]
  u16* wt_fc1  = (u16*)(ws + 1048576);   // [1024][256]
  u16* wt_fc2  = (u16*)(ws + 1572864);   // [256][1024]
  u16* x_hi    = (u16*)(ws + 2097152);   // [4096][256]
  u16* x_lo    = (u16*)(ws + 4194304);
  u16* q_hi    = (u16*)(ws + 6291456);
  u16* q_lo    = (u16*)(ws + 8388608);
  u16* k_hi    = (u16*)(ws + 10485760);
  u16* k_lo    = (u16*)(ws + 12582912);
  u16* vt      = (u16*)(ws + 14680064);  // [16 bh][32 d][2048 n]; end 16MB
  u16* attn    = (u16*)d_out;            // first 2MB of d_out = attn scratch (bf16)
  float* projf = (float*)(ws + 6291456); // 4MB fp32 over dead Q
  u16* net     = (u16*)(ws + 14680064);  // 2MB over dead vt
  u16* hbuf    = (u16*)(ws + 2097152);   // 8MB over dead x/projf

  prep_k<<<7176, 256, 0, stream>>>(x, qkv_w, proj_w, fc1_w, fc2_w,
                                   proj_b, fc1_b, fc2_b, ln_g, ln_b,
                                   x_hi, x_lo, wq_hi, wq_lo, wt_proj, wt_fc1, wt_fc2,
                                   b_proj, b_fc1, b_fc2, g_ln, bb_ln);

  // qkv = x @ qkv_w, 3-term hi/lo (V cols plain) -> q hi/lo, k hi/lo, vt
  gemm_k<4, 2, false, false, true><<<dim3(6, 32), 256, 0, stream>>>(
      x_hi, wq_hi, x_lo, wq_lo, nullptr, nullptr, vt, q_hi, q_lo, k_hi, k_lo, 4096, 768, 256);
  attn_k<<<512, 256, 0, stream>>>(q_hi, q_lo, k_hi, k_lo, vt, attn);
  // proj (+bias) -> fp32
  gemm_k<2, 0, true, false, false><<<dim3(4, 64), 256, 0, stream>>>(
      attn, wt_proj, nullptr, nullptr, b_proj, nullptr, projf,
      nullptr, nullptr, nullptr, nullptr, 4096, 256, 256);
  ln_k<<<4096, 256, 0, stream>>>(projf, x_hi, x_lo, g_ln, bb_ln, net);
  // fc1 (+bias)
  gemm_k<4, 1, true, false, false><<<dim3(8, 32), 256, 0, stream>>>(
      net, wt_fc1, nullptr, nullptr, b_fc1, nullptr, hbuf,
      nullptr, nullptr, nullptr, nullptr, 4096, 1024, 256);
  // fc2 (+bias +shortcut) -> d_out fp32
  gemm_k<2, 0, true, true, false><<<dim3(4, 64), 256, 0, stream>>>(
      hbuf, wt_fc2, nullptr, nullptr, b_fc2, net, d_out,
      nullptr, nullptr, nullptr, nullptr, 4096, 256, 1024);
}

// Round 10
// 179.268 us; speedup vs baseline: 3.6580x; 1.0723x over previous
//
#include <hip/hip_runtime.h>

// B=2,N=2048,D=256,H=8,HD=32,DFF=1024. SCALE MULTIPLIES by sqrt(32). No MLP
// activation. Post-norm. Inputs fp32 (auto-detected), output fp32.
// Verified R5-R9: absmax 0.031 vs threshold 0.134.
//
// R10: (1) split-K x2 flash attention (R9 was 2 waves/SIMD, latency-starved:
// 4200 cyc/iter vs ~1200 resource floor). 1024 blocks, per-chunk normalized
// O_c -> d_out halves (bf16) + mu = m*CL + log2(l) fp32 at ws+16M (ws_size
// checked; fallback = R9 kernel). combine_k merges. (2) qkv/fc1 GEMMs to
// TW=2 (768/1024 blocks; were 192/256 = latency-bound at <=1 block/CU).

typedef __attribute__((ext_vector_type(8))) short short8;   // 8 bf16 = 4 VGPRs
typedef __attribute__((ext_vector_type(4))) short bf16x4;   // 4 bf16 = 2 VGPRs
typedef __attribute__((ext_vector_type(4))) float floatx4;
typedef unsigned short u16;

#define MFMA32(a,b,c) __builtin_amdgcn_mfma_f32_16x16x32_bf16((a),(b),(c),0,0,0)
#if __has_builtin(__builtin_amdgcn_mfma_f32_16x16x16_bf16)
#define MFMAPV(a,b,c) __builtin_amdgcn_mfma_f32_16x16x16_bf16((a),(b),(c),0,0,0)
#else
#define MFMAPV(a,b,c) __builtin_amdgcn_mfma_f32_16x16x16bf16_1k((a),(b),(c),0,0,0)
#endif
#define CLF 8.1615404f   // SCALE * log2(e) = 5.65685 * 1.442695

__device__ __forceinline__ float bf2f(u16 u) { return __uint_as_float(((unsigned)u) << 16); }
__device__ __forceinline__ u16 f2bf(float f) {            // RNE
  unsigned u = __float_as_uint(f);
  u += 0x7fffu + ((u >> 16) & 1u);
  return (u16)(u >> 16);
}
// async global->LDS, 16B/lane; LDS dest must be wave-uniform base + lane*16 (m104)
__device__ __forceinline__ void gll16(const void* g, void* l) {
  __builtin_amdgcn_global_load_lds((const __attribute__((address_space(1))) void*)g,
                                   (__attribute__((address_space(3))) void*)l, 16, 0, 0);
}

// ---------------- fused preamble: dtype-detect + canonicalize all inputs ----------------
__global__ __launch_bounds__(256) void prep_k(
    const void* __restrict__ x, const void* __restrict__ qkv_w,
    const void* __restrict__ proj_w, const void* __restrict__ fc1_w,
    const void* __restrict__ fc2_w, const void* __restrict__ proj_b,
    const void* __restrict__ fc1_b, const void* __restrict__ fc2_b,
    const void* __restrict__ ln_g, const void* __restrict__ ln_b,
    u16* __restrict__ x_hi, u16* __restrict__ x_lo,
    u16* __restrict__ wq_hi, u16* __restrict__ wq_lo,
    u16* __restrict__ wt_proj, u16* __restrict__ wt_fc1, u16* __restrict__ wt_fc2,
    u16* __restrict__ b_proj, u16* __restrict__ b_fc1, u16* __restrict__ b_fc2,
    u16* __restrict__ g_ln, u16* __restrict__ bb_ln)
{
  const int lane = threadIdx.x & 63;
  const float probe = bf2f(((const u16*)qkv_w)[lane]);
  const bool f32 = __ballot(!(fabsf(probe) < 1000.0f)) != 0ull;
  const int bid = blockIdx.x, tid = threadIdx.x;
  #define RD(p, i) (f32 ? ((const float*)(p))[i] : bf2f(((const u16*)(p))[i]))
  if (bid < 4096) {               // x -> hi+lo
    const size_t i = (size_t)bid * 256 + tid;
    const float f = RD(x, i); const u16 h = f2bf(f);
    x_hi[i] = h; x_lo[i] = f2bf(f - bf2f(h));
  } else if (bid < 4864) {        // qkv_w^T -> hi+lo ([768][256])
    const int idx = (bid - 4096) * 256 + tid;
    const int n = idx >> 8, k = idx & 255;
    const float f = RD(qkv_w, (size_t)k * 768 + n); const u16 h = f2bf(f);
    wq_hi[idx] = h; wq_lo[idx] = f2bf(f - bf2f(h));
  } else if (bid < 5120) {        // proj_w^T ([256][256])
    const int idx = (bid - 4864) * 256 + tid;
    wt_proj[idx] = f2bf(RD(proj_w, (size_t)(idx & 255) * 256 + (idx >> 8)));
  } else if (bid < 6144) {        // fc1_w^T ([1024][256])
    const int idx = (bid - 5120) * 256 + tid;
    wt_fc1[idx] = f2bf(RD(fc1_w, (size_t)(idx & 255) * 1024 + (idx >> 8)));
  } else if (bid < 7168) {        // fc2_w^T ([256][1024])
    const int idx = (bid - 6144) * 256 + tid;
    wt_fc2[idx] = f2bf(RD(fc2_w, (size_t)(idx & 1023) * 256 + (idx >> 10)));
  } else {                        // biases + LN params
    const int j = (bid - 7168) * 256 + tid;
    if (j < 256)       b_proj[j]        = f2bf(RD(proj_b, j));
    else if (j < 1280) b_fc1[j - 256]   = f2bf(RD(fc1_b, j - 256));
    else if (j < 1536) b_fc2[j - 1280]  = f2bf(RD(fc2_b, j - 1280));
    else if (j < 1792) g_ln[j - 1536]   = f2bf(RD(ln_g, j - 1536));
    else               bb_ln[j - 1792]  = f2bf(RD(ln_b, j - 1792));
  }
  #undef RD
}

// ---------------- GEMM: C[M,Nn] = A[M,K] * Bt[Nn,K]^T  (bf16, fp32 accum) -----------
template<int TW, int EPI, bool BIAS, bool RES, bool SPLIT>
__global__ __launch_bounds__(256) void gemm_k(
    const u16* __restrict__ A, const u16* __restrict__ Bt,
    const u16* __restrict__ A2, const u16* __restrict__ B2,
    const u16* __restrict__ bias, const u16* __restrict__ res,
    void* __restrict__ out0, u16* __restrict__ aux1, u16* __restrict__ aux2,
    u16* __restrict__ aux3, u16* __restrict__ aux4,
    int M, int Nn, int K)
{
  constexpr int BT = TW * 32;
  __shared__ __align__(16) short As[BT][40];
  __shared__ __align__(16) short Bs[BT][40];
  __shared__ __align__(16) short As2[SPLIT ? BT : 1][40];
  __shared__ __align__(16) short Bs2[SPLIT ? BT : 1][40];
  const int tid = threadIdx.x;
  const int m0 = blockIdx.y * BT, n0 = blockIdx.x * BT;
  const bool sp = SPLIT && (n0 < 512);
  const int wid = tid >> 6, lane = tid & 63;
  const int wm = (wid >> 1) * (TW * 16), wn = (wid & 1) * (TW * 16);
  const int lm = lane & 15, quad = lane >> 4;

  floatx4 zero = {0.f, 0.f, 0.f, 0.f};
  floatx4 acc[TW][TW];
#pragma unroll
  for (int i = 0; i < TW; ++i)
#pragma unroll
    for (int j = 0; j < TW; ++j) acc[i][j] = zero;

  for (int k0 = 0; k0 < K; k0 += 32) {
#pragma unroll
    for (int c = 0; c < (TW > 1 ? TW / 2 : 1); ++c) {
      int cid = tid * (TW > 1 ? TW / 2 : 1) + c;
      int row = cid >> 2, off = (cid & 3) * 8;
      const size_t ga = (size_t)(m0 + row) * K + k0 + off;
      const size_t gb = (size_t)(n0 + row) * K + k0 + off;
      *(short8*)&As[row][off] = *(const short8*)&A[ga];
      *(short8*)&Bs[row][off] = *(const short8*)&Bt[gb];
      if (sp) {
        *(short8*)&As2[row][off] = *(const short8*)&A2[ga];
        *(short8*)&Bs2[row][off] = *(const short8*)&B2[gb];
      }
    }
    __syncthreads();
    short8 fa[TW], fb[TW], fa2[TW], fb2[TW];
#pragma unroll
    for (int t = 0; t < TW; ++t) {
      fa[t] = *(const short8*)&As[wm + t * 16 + lm][quad * 8];
      fb[t] = *(const short8*)&Bs[wn + t * 16 + lm][quad * 8];
      if (sp) {
        fa2[t] = *(const short8*)&As2[wm + t * 16 + lm][quad * 8];
        fb2[t] = *(const short8*)&Bs2[wn + t * 16 + lm][quad * 8];
      }
    }
#pragma unroll
    for (int i = 0; i < TW; ++i)
#pragma unroll
      for (int j = 0; j < TW; ++j) {
        if (sp) {
          acc[i][j] = MFMA32(fa[i], fb2[j], acc[i][j]);
          acc[i][j] = MFMA32(fa2[i], fb[j], acc[i][j]);
        }
        acc[i][j] = MFMA32(fa[i], fb[j], acc[i][j]);
      }
    __syncthreads();
  }

#pragma unroll
  for (int i = 0; i < TW; ++i) {
    const int rowb = m0 + wm + i * 16 + quad * 4;
#pragma unroll
    for (int j = 0; j < TW; ++j) {
      const int col = n0 + wn + j * 16 + lm;
      const float bv = BIAS ? bf2f(bias[col]) : 0.f;
#pragma unroll
      for (int r = 0; r < 4; ++r) {
        const int row = rowb + r;
        float v = acc[i][j][r] + bv;
        const size_t o = (size_t)row * Nn + col;
        if (RES) v += bf2f(res[o]);
        if (EPI == 0) {
          ((float*)out0)[o] = v;
        } else if (EPI == 1) {
          ((u16*)out0)[o] = f2bf(v);
        } else {
          u16 hi = f2bf(v);
          u16 lo = f2bf(v - bf2f(hi));
          if (col < 256) {
            const size_t oq = (size_t)row * 256 + col;
            aux1[oq] = hi; aux2[oq] = lo;       // Q
          } else if (col < 512) {
            const size_t ok = (size_t)row * 256 + (col - 256);
            aux3[ok] = hi; aux4[ok] = lo;       // K
          } else {                              // V -> per-head transposed [bh][32][2048]
            int d = col & 31, hh = (col >> 5) & 7;
            int bb = row >> 11, n = row & 2047;
            ((u16*)out0)[(size_t)((bb * 8 + hh) * 32 + d) * 2048 + n] = hi;
          }
        }
      }
    }
  }
}

// ---------------- flash attention v4: split-K x2, S^T form, register-direct P ----
// CHUNKS=2: blockIdx bit9 = key chunk; writes per-chunk normalized O (bf16) to
// outp + chunk*1M u16, and mu = m*CLF + log2(l) (fp32) for the combine.
// CHUNKS=1: R9 behaviour (no mu, full 2048 keys), used when ws too small.
template<int CHUNKS>
__global__ __launch_bounds__(256) void attn_k(
    const u16* __restrict__ qhi, const u16* __restrict__ qlo,
    const u16* __restrict__ khi, const u16* __restrict__ klo,
    const u16* __restrict__ vt, u16* __restrict__ outp, float* __restrict__ mu)
{
  __shared__ __align__(16) u16 Khi[2][64][32];   // [buf][key][d]
  __shared__ __align__(16) u16 Klo[2][64][32];
  __shared__ __align__(16) u16 Vs [2][32][64];   // [buf][d][key], key-octet ^ (d&7)
  const int tid = threadIdx.x, wid = tid >> 6, lane = tid & 63;
  const int lm = lane & 15, quad = lane >> 4;
  const int bid = blockIdx.x;
  const int chunk = (CHUNKS == 2) ? (bid >> 9) : 0;
  const int qblk = bid & 31, bh = (bid >> 5) & 15;
  const int b = bh >> 3, h = bh & 7;
  const int q0 = qblk * 64 + wid * 16;
  const size_t tb = (size_t)b * 2048;
  const int NT = (CHUNKS == 2) ? 16 : 32;        // K-tiles per block
  const int kofs = chunk * 1024;                 // first key of this chunk

  short8 qh, ql;   // Q^T B-frag (k=d=quad*8+j, n=qrow=lm)
  { size_t off = (tb + q0 + lm) * 256 + h * 32 + quad * 8;
    qh = *(const short8*)&qhi[off];
    ql = *(const short8*)&qlo[off]; }

  const int kkey = tid >> 2, kg = tid & 3;                  // K: [key][d-octet]
  const size_t kb = (tb + kofs + kkey) * 256 + h * 32 + kg * 8;
  const int vd = tid >> 3, vp = tid & 7, vk8 = vp ^ (vd & 7);
  const size_t vb = (size_t)(bh * 32 + vd) * 2048 + kofs + vk8 * 8;

  gll16(khi + kb, (u16*)Khi + tid * 8);
  gll16(klo + kb, (u16*)Klo + tid * 8);
  gll16(vt  + vb, (u16*)Vs  + tid * 8);

  float mrun = -1e30f, lrun = 0.f;
  floatx4 o0 = {0.f,0.f,0.f,0.f}, o1 = {0.f,0.f,0.f,0.f};

  for (int kt = 0; kt < NT; ++kt) {
    const int buf = kt & 1;
    __syncthreads();             // implicit vmcnt(0): tile kt resident
    if (kt < NT - 1) {           // stage kt+1 -> buf^1
      const int nb = (buf ^ 1) * 2048;
      const size_t ko = (size_t)(kt + 1) * 16384;
      const size_t vo = (size_t)(kt + 1) * 64;
      gll16(khi + kb + ko, (u16*)Khi + nb + tid * 8);
      gll16(klo + kb + ko, (u16*)Klo + nb + tid * 8);
      gll16(vt  + vb + vo, (u16*)Vs  + nb + tid * 8);
    }

    // S^T tile kf: A = K strip, B = Q^T. Raw z (unscaled).
    floatx4 z[4];
#pragma unroll
    for (int kf = 0; kf < 4; ++kf) {
      short8 khf = *(const short8*)&Khi[buf][kf * 16 + lm][quad * 8];
      short8 klf = *(const short8*)&Klo[buf][kf * 16 + lm][quad * 8];
      floatx4 zz = {0.f,0.f,0.f,0.f};
      zz = MFMA32(khf, ql, zz);
      zz = MFMA32(klf, qh, zz);
      zz = MFMA32(khf, qh, zz);
      z[kf] = zz;
    }
    float zm = fmaxf(fmaxf(fmaxf(z[0][0], z[0][1]), fmaxf(z[0][2], z[0][3])),
               fmaxf(fmaxf(z[1][0], z[1][1]), fmaxf(z[1][2], z[1][3])));
    zm = fmaxf(zm, fmaxf(fmaxf(fmaxf(z[2][0], z[2][1]), fmaxf(z[2][2], z[2][3])),
                   fmaxf(fmaxf(z[3][0], z[3][1]), fmaxf(z[3][2], z[3][3]))));
    zm = fmaxf(zm, __shfl_xor(zm, 16));
    zm = fmaxf(zm, __shfl_xor(zm, 32));
    const float mn = fmaxf(mrun, zm);
    const float alpha = exp2f((mrun - mn) * CLF);
    const float mc = mn * CLF;
    mrun = mn;
    float ls = 0.f;
    bf16x4 pb[4];
#pragma unroll
    for (int kf = 0; kf < 4; ++kf)
#pragma unroll
      for (int r = 0; r < 4; ++r) {
        const float p = exp2f(__builtin_fmaf(z[kf][r], CLF, -mc));
        ls += p;
        pb[kf][r] = (short)f2bf(p);
      }
    ls += __shfl_xor(ls, 16);
    ls += __shfl_xor(ls, 32);
    lrun = lrun * alpha + ls;
#pragma unroll
    for (int r = 0; r < 4; ++r) { o0[r] *= alpha; o1[r] *= alpha; }
    const u16* vbase = (const u16*)Vs + buf * 2048;
#pragma unroll
    for (int kf = 0; kf < 4; ++kf) {
      const int k8 = 2 * kf + (quad >> 1);
      const int d0 = lm, d1 = 16 + lm;
      bf16x4 vf0 = *(const bf16x4*)(vbase + (d0 * 8 + (k8 ^ (d0 & 7))) * 8 + (quad & 1) * 4);
      bf16x4 vf1 = *(const bf16x4*)(vbase + (d1 * 8 + (k8 ^ (d1 & 7))) * 8 + (quad & 1) * 4);
      o0 = MFMAPV(vf0, pb[kf], o0);
      o1 = MFMAPV(vf1, pb[kf], o1);
    }
  }
  // epilogue: O^T C-layout: qrow=lm, d = chunk16*16 + quad*4 + r
  const float inv = 1.0f / lrun;
  const size_t tok = tb + q0 + lm;
  const size_t rowo = (size_t)chunk * 1048576 + tok * 256 + h * 32;
#pragma unroll
  for (int r = 0; r < 4; ++r) {
    outp[rowo + quad * 4 + r]      = f2bf(o0[r] * inv);
    outp[rowo + 16 + quad * 4 + r] = f2bf(o1[r] * inv);
  }
  if (CHUNKS == 2 && quad == 0)
    mu[chunk * 32768 + tok * 8 + h] = __builtin_fmaf(mrun, CLF, __log2f(lrun));
}

// ---------------- combine: softmax-weighted merge of the 2 key-chunks (in-place) ----
__global__ __launch_bounds__(256) void combine_k(u16* __restrict__ d,
                                                 const float* __restrict__ mu)
{
  const int t = blockIdx.x, c = threadIdx.x, h = c >> 5;
  const size_t o = (size_t)t * 256 + c;
  const float m0 = mu[t * 8 + h], m1 = mu[32768 + t * 8 + h];
  const float M = fmaxf(m0, m1);
  const float w0 = exp2f(m0 - M), w1 = exp2f(m1 - M);
  d[o] = f2bf((w0 * bf2f(d[o]) + w1 * bf2f(d[o + 1048576])) / (w0 + w1));
}

// ---------------- residual add + LayerNorm: net = LN(projf + x) ----------------
__global__ __launch_bounds__(256) void ln_k(const float* __restrict__ pf,
                                            const u16* __restrict__ xh,
                                            const u16* __restrict__ xl,
                                            const u16* __restrict__ g,
                                            const u16* __restrict__ bta,
                                            u16* __restrict__ net)
{
  const int t = blockIdx.x, c = threadIdx.x;
  const size_t o = (size_t)t * 256 + c;
  float v = pf[o] + bf2f(xh[o]) + bf2f(xl[o]);
  float s = v, s2 = v * v;
#pragma unroll
  for (int d = 1; d < 64; d <<= 1) { s += __shfl_xor(s, d); s2 += __shfl_xor(s2, d); }
  __shared__ float ss[4], ss2[4];
  const int w = c >> 6;
  if ((c & 63) == 0) { ss[w] = s; ss2[w] = s2; }
  __syncthreads();
  s = ss[0] + ss[1] + ss[2] + ss[3];
  s2 = ss2[0] + ss2[1] + ss2[2] + ss2[3];
  const float mu = s * (1.f / 256.f);
  const float var = s2 * (1.f / 256.f) - mu * mu;
  const float is = rsqrtf(var + 1e-5f);
  net[o] = f2bf((v - mu) * is * bf2f(g[c]) + bf2f(bta[c]));
}

extern "C" void kernel_launch(void* const* d_in, const int* in_sizes, int n_in,
                              void* d_out, int out_size, void* d_ws, size_t ws_size,
                              hipStream_t stream) {
  const void* x      = d_in[0];
  const void* qkv_w  = d_in[1];
  const void* proj_w = d_in[2];
  const void* proj_b = d_in[3];
  const void* fc1_w  = d_in[4];
  const void* fc1_b  = d_in[5];
  const void* fc2_w  = d_in[6];
  const void* fc2_b  = d_in[7];
  const void* ln_g   = d_in[8];
  const void* ln_b   = d_in[9];

  char* ws = (char*)d_ws;
  u16* b_proj  = (u16*)(ws + 4096);
  u16* b_fc1   = (u16*)(ws + 8192);
  u16* b_fc2   = (u16*)(ws + 12288);
  u16* g_ln    = (u16*)(ws + 16384);
  u16* bb_ln   = (u16*)(ws + 20480);
  u16* wq_hi   = (u16*)(ws + 131072);    // [768][256]
  u16* wq_lo   = (u16*)(ws + 524288);
  u16* wt_proj = (u16*)(ws + 917504);    // [256][256]
  u16* wt_fc1  = (u16*)(ws + 1048576);   // [1024][256]
  u16* wt_fc2  = (u16*)(ws + 1572864);   // [256][1024]
  u16* x_hi    = (u16*)(ws + 2097152);   // [4096][256]
  u16* x_lo    = (u16*)(ws + 4194304);
  u16* q_hi    = (u16*)(ws + 6291456);
  u16* q_lo    = (u16*)(ws + 8388608);
  u16* k_hi    = (u16*)(ws + 10485760);
  u16* k_lo    = (u16*)(ws + 12582912);
  u16* vt      = (u16*)(ws + 14680064);  // [16 bh][32 d][2048 n]; end 16M
  float* mu    = (float*)(ws + 16777216);// [2][4096][8] fp32, 256KB (if ws allows)
  u16* attn    = (u16*)d_out;            // d_out = attn scratch (2 chunks x 2MB bf16)
  float* projf = (float*)(ws + 6291456); // 4MB fp32 over dead Q
  u16* net     = (u16*)(ws + 14680064);  // 2MB over dead vt
  u16* hbuf    = (u16*)(ws + 2097152);   // 8MB over dead x/projf

  const bool splitk = ws_size >= (16777216 + 262144);  // call-invariant -> graph-safe

  prep_k<<<7176, 256, 0, stream>>>(x, qkv_w, proj_w, fc1_w, fc2_w,
                                   proj_b, fc1_b, fc2_b, ln_g, ln_b,
                                   x_hi, x_lo, wq_hi, wq_lo, wt_proj, wt_fc1, wt_fc2,
                                   b_proj, b_fc1, b_fc2, g_ln, bb_ln);

  // qkv = x @ qkv_w, 3-term hi/lo (V cols plain) -> q hi/lo, k hi/lo, vt
  gemm_k<2, 2, false, false, true><<<dim3(12, 64), 256, 0, stream>>>(
      x_hi, wq_hi, x_lo, wq_lo, nullptr, nullptr, vt, q_hi, q_lo, k_hi, k_lo, 4096, 768, 256);
  if (splitk) {
    attn_k<2><<<1024, 256, 0, stream>>>(q_hi, q_lo, k_hi, k_lo, vt, attn, mu);
    combine_k<<<4096, 256, 0, stream>>>(attn, mu);
  } else {
    attn_k<1><<<512, 256, 0, stream>>>(q_hi, q_lo, k_hi, k_lo, vt, attn, nullptr);
  }
  // proj (+bias) -> fp32
  gemm_k<2, 0, true, false, false><<<dim3(4, 64), 256, 0, stream>>>(
      attn, wt_proj, nullptr, nullptr, b_proj, nullptr, projf,
      nullptr, nullptr, nullptr, nullptr, 4096, 256, 256);
  ln_k<<<4096, 256, 0, stream>>>(projf, x_hi, x_lo, g_ln, bb_ln, net);
  // fc1 (+bias)
  gemm_k<2, 1, true, false, false><<<dim3(16, 64), 256, 0, stream>>>(
      net, wt_fc1, nullptr, nullptr, b_fc1, nullptr, hbuf,
      nullptr, nullptr, nullptr, nullptr, 4096, 1024, 256);
  // fc2 (+bias +shortcut) -> d_out fp32
  gemm_k<2, 0, true, true, false><<<dim3(4, 64), 256, 0, stream>>>(
      hbuf, wt_fc2, nullptr, nullptr, b_fc2, net, d_out,
      nullptr, nullptr, nullptr, nullptr, 4096, 256, 1024);
}

// Round 11
// 169.540 us; speedup vs baseline: 3.8679x; 1.0574x over previous
//
#include <hip/hip_runtime.h>

// B=2,N=2048,D=256,H=8,HD=32,DFF=1024. SCALE MULTIPLIES by sqrt(32). No MLP
// activation. Post-norm. Inputs fp32 (auto-detected), output fp32.
// Verified R5-R10: absmax 0.031 vs threshold 0.134.
//
// R11: (1) attn split-K x4 (512 keys/chunk): 2048 blocks -> ~6 blocks/CU
// (LDS-capped) vs R10's 30% occupancy. Chunks 2,3 -> ws scratch past mu
// (ws_size-checked; fallback x2 -> x1). 4-way log2-domain combine.
// (2) gemm_k register-prefetch: issue next tile's global loads right after
// the LDS-write barrier so they fly during the MFMAs (GEMMs run at 1-4
// blocks/CU -- no TLP to hide load latency; this is the ILP fix).

typedef __attribute__((ext_vector_type(8))) short short8;   // 8 bf16 = 4 VGPRs
typedef __attribute__((ext_vector_type(4))) short bf16x4;   // 4 bf16 = 2 VGPRs
typedef __attribute__((ext_vector_type(4))) float floatx4;
typedef unsigned short u16;

#define MFMA32(a,b,c) __builtin_amdgcn_mfma_f32_16x16x32_bf16((a),(b),(c),0,0,0)
#if __has_builtin(__builtin_amdgcn_mfma_f32_16x16x16_bf16)
#define MFMAPV(a,b,c) __builtin_amdgcn_mfma_f32_16x16x16_bf16((a),(b),(c),0,0,0)
#else
#define MFMAPV(a,b,c) __builtin_amdgcn_mfma_f32_16x16x16bf16_1k((a),(b),(c),0,0,0)
#endif
#define CLF 8.1615404f   // SCALE * log2(e) = 5.65685 * 1.442695

__device__ __forceinline__ float bf2f(u16 u) { return __uint_as_float(((unsigned)u) << 16); }
__device__ __forceinline__ u16 f2bf(float f) {            // RNE
  unsigned u = __float_as_uint(f);
  u += 0x7fffu + ((u >> 16) & 1u);
  return (u16)(u >> 16);
}
// async global->LDS, 16B/lane; LDS dest must be wave-uniform base + lane*16 (m104)
__device__ __forceinline__ void gll16(const void* g, void* l) {
  __builtin_amdgcn_global_load_lds((const __attribute__((address_space(1))) void*)g,
                                   (__attribute__((address_space(3))) void*)l, 16, 0, 0);
}

// ---------------- fused preamble: dtype-detect + canonicalize all inputs ----------------
__global__ __launch_bounds__(256) void prep_k(
    const void* __restrict__ x, const void* __restrict__ qkv_w,
    const void* __restrict__ proj_w, const void* __restrict__ fc1_w,
    const void* __restrict__ fc2_w, const void* __restrict__ proj_b,
    const void* __restrict__ fc1_b, const void* __restrict__ fc2_b,
    const void* __restrict__ ln_g, const void* __restrict__ ln_b,
    u16* __restrict__ x_hi, u16* __restrict__ x_lo,
    u16* __restrict__ wq_hi, u16* __restrict__ wq_lo,
    u16* __restrict__ wt_proj, u16* __restrict__ wt_fc1, u16* __restrict__ wt_fc2,
    u16* __restrict__ b_proj, u16* __restrict__ b_fc1, u16* __restrict__ b_fc2,
    u16* __restrict__ g_ln, u16* __restrict__ bb_ln)
{
  const int lane = threadIdx.x & 63;
  const float probe = bf2f(((const u16*)qkv_w)[lane]);
  const bool f32 = __ballot(!(fabsf(probe) < 1000.0f)) != 0ull;
  const int bid = blockIdx.x, tid = threadIdx.x;
  #define RD(p, i) (f32 ? ((const float*)(p))[i] : bf2f(((const u16*)(p))[i]))
  if (bid < 4096) {               // x -> hi+lo
    const size_t i = (size_t)bid * 256 + tid;
    const float f = RD(x, i); const u16 h = f2bf(f);
    x_hi[i] = h; x_lo[i] = f2bf(f - bf2f(h));
  } else if (bid < 4864) {        // qkv_w^T -> hi+lo ([768][256])
    const int idx = (bid - 4096) * 256 + tid;
    const int n = idx >> 8, k = idx & 255;
    const float f = RD(qkv_w, (size_t)k * 768 + n); const u16 h = f2bf(f);
    wq_hi[idx] = h; wq_lo[idx] = f2bf(f - bf2f(h));
  } else if (bid < 5120) {        // proj_w^T ([256][256])
    const int idx = (bid - 4864) * 256 + tid;
    wt_proj[idx] = f2bf(RD(proj_w, (size_t)(idx & 255) * 256 + (idx >> 8)));
  } else if (bid < 6144) {        // fc1_w^T ([1024][256])
    const int idx = (bid - 5120) * 256 + tid;
    wt_fc1[idx] = f2bf(RD(fc1_w, (size_t)(idx & 255) * 1024 + (idx >> 8)));
  } else if (bid < 7168) {        // fc2_w^T ([256][1024])
    const int idx = (bid - 6144) * 256 + tid;
    wt_fc2[idx] = f2bf(RD(fc2_w, (size_t)(idx & 1023) * 256 + (idx >> 10)));
  } else {                        // biases + LN params
    const int j = (bid - 7168) * 256 + tid;
    if (j < 256)       b_proj[j]        = f2bf(RD(proj_b, j));
    else if (j < 1280) b_fc1[j - 256]   = f2bf(RD(fc1_b, j - 256));
    else if (j < 1536) b_fc2[j - 1280]  = f2bf(RD(fc2_b, j - 1280));
    else if (j < 1792) g_ln[j - 1536]   = f2bf(RD(ln_g, j - 1536));
    else               bb_ln[j - 1792]  = f2bf(RD(ln_b, j - 1792));
  }
  #undef RD
}

// ---------------- GEMM with register-prefetch staging ----------------
template<int TW, int EPI, bool BIAS, bool RES, bool SPLIT>
__global__ __launch_bounds__(256) void gemm_k(
    const u16* __restrict__ A, const u16* __restrict__ Bt,
    const u16* __restrict__ A2, const u16* __restrict__ B2,
    const u16* __restrict__ bias, const u16* __restrict__ res,
    void* __restrict__ out0, u16* __restrict__ aux1, u16* __restrict__ aux2,
    u16* __restrict__ aux3, u16* __restrict__ aux4,
    int M, int Nn, int K)
{
  constexpr int BT = TW * 32;
  constexpr int NC = (TW > 1 ? TW / 2 : 1);
  __shared__ __align__(16) short As[BT][40];
  __shared__ __align__(16) short Bs[BT][40];
  __shared__ __align__(16) short As2[SPLIT ? BT : 1][40];
  __shared__ __align__(16) short Bs2[SPLIT ? BT : 1][40];
  const int tid = threadIdx.x;
  const int m0 = blockIdx.y * BT, n0 = blockIdx.x * BT;
  const bool sp = SPLIT && (n0 < 512);
  const int wid = tid >> 6, lane = tid & 63;
  const int wm = (wid >> 1) * (TW * 16), wn = (wid & 1) * (TW * 16);
  const int lm = lane & 15, quad = lane >> 4;

  floatx4 zero = {0.f, 0.f, 0.f, 0.f};
  floatx4 acc[TW][TW];
#pragma unroll
  for (int i = 0; i < TW; ++i)
#pragma unroll
    for (int j = 0; j < TW; ++j) acc[i][j] = zero;

  int srow[NC], soff[NC];
  short8 ra[NC], rb[NC], ra2[NC], rb2[NC];
#pragma unroll
  for (int c = 0; c < NC; ++c) {
    const int cid = tid * NC + c;
    srow[c] = cid >> 2; soff[c] = (cid & 3) * 8;
  }
  // prefetch tile 0
#pragma unroll
  for (int c = 0; c < NC; ++c) {
    const size_t ga = (size_t)(m0 + srow[c]) * K + soff[c];
    const size_t gb = (size_t)(n0 + srow[c]) * K + soff[c];
    ra[c] = *(const short8*)&A[ga];  rb[c] = *(const short8*)&Bt[gb];
    if (sp) { ra2[c] = *(const short8*)&A2[ga]; rb2[c] = *(const short8*)&B2[gb]; }
  }

  for (int k0 = 0; k0 < K; k0 += 32) {
    if (k0) __syncthreads();             // prev compute done reading LDS
#pragma unroll
    for (int c = 0; c < NC; ++c) {
      *(short8*)&As[srow[c]][soff[c]] = ra[c];
      *(short8*)&Bs[srow[c]][soff[c]] = rb[c];
      if (sp) {
        *(short8*)&As2[srow[c]][soff[c]] = ra2[c];
        *(short8*)&Bs2[srow[c]][soff[c]] = rb2[c];
      }
    }
    __syncthreads();
    if (k0 + 32 < K) {                   // issue next tile loads: fly during MFMAs
#pragma unroll
      for (int c = 0; c < NC; ++c) {
        const size_t ga = (size_t)(m0 + srow[c]) * K + k0 + 32 + soff[c];
        const size_t gb = (size_t)(n0 + srow[c]) * K + k0 + 32 + soff[c];
        ra[c] = *(const short8*)&A[ga];  rb[c] = *(const short8*)&Bt[gb];
        if (sp) { ra2[c] = *(const short8*)&A2[ga]; rb2[c] = *(const short8*)&B2[gb]; }
      }
    }
    short8 fa[TW], fb[TW], fa2[TW], fb2[TW];
#pragma unroll
    for (int t = 0; t < TW; ++t) {
      fa[t] = *(const short8*)&As[wm + t * 16 + lm][quad * 8];
      fb[t] = *(const short8*)&Bs[wn + t * 16 + lm][quad * 8];
      if (sp) {
        fa2[t] = *(const short8*)&As2[wm + t * 16 + lm][quad * 8];
        fb2[t] = *(const short8*)&Bs2[wn + t * 16 + lm][quad * 8];
      }
    }
#pragma unroll
    for (int i = 0; i < TW; ++i)
#pragma unroll
      for (int j = 0; j < TW; ++j) {
        if (sp) {
          acc[i][j] = MFMA32(fa[i], fb2[j], acc[i][j]);
          acc[i][j] = MFMA32(fa2[i], fb[j], acc[i][j]);
        }
        acc[i][j] = MFMA32(fa[i], fb[j], acc[i][j]);
      }
  }

#pragma unroll
  for (int i = 0; i < TW; ++i) {
    const int rowb = m0 + wm + i * 16 + quad * 4;
#pragma unroll
    for (int j = 0; j < TW; ++j) {
      const int col = n0 + wn + j * 16 + lm;
      const float bv = BIAS ? bf2f(bias[col]) : 0.f;
#pragma unroll
      for (int r = 0; r < 4; ++r) {
        const int row = rowb + r;
        float v = acc[i][j][r] + bv;
        const size_t o = (size_t)row * Nn + col;
        if (RES) v += bf2f(res[o]);
        if (EPI == 0) {
          ((float*)out0)[o] = v;
        } else if (EPI == 1) {
          ((u16*)out0)[o] = f2bf(v);
        } else {
          u16 hi = f2bf(v);
          u16 lo = f2bf(v - bf2f(hi));
          if (col < 256) {
            const size_t oq = (size_t)row * 256 + col;
            aux1[oq] = hi; aux2[oq] = lo;       // Q
          } else if (col < 512) {
            const size_t ok = (size_t)row * 256 + (col - 256);
            aux3[ok] = hi; aux4[ok] = lo;       // K
          } else {                              // V -> per-head transposed [bh][32][2048]
            int d = col & 31, hh = (col >> 5) & 7;
            int bb = row >> 11, n = row & 2047;
            ((u16*)out0)[(size_t)((bb * 8 + hh) * 32 + d) * 2048 + n] = hi;
          }
        }
      }
    }
  }
}

// ---------------- flash attention v5: split-K x CHUNKS, S^T form ----
// chunk c covers keys [c*2048/CHUNKS, ...). Per-chunk normalized O (bf16):
// chunks 0,1 -> outp (d_out), chunks 2,3 -> out23 (ws scratch). mu = m*CLF+log2(l).
template<int CHUNKS>
__global__ __launch_bounds__(256) void attn_k(
    const u16* __restrict__ qhi, const u16* __restrict__ qlo,
    const u16* __restrict__ khi, const u16* __restrict__ klo,
    const u16* __restrict__ vt, u16* __restrict__ outp, u16* __restrict__ out23,
    float* __restrict__ mu)
{
  __shared__ __align__(16) u16 Khi[2][64][32];   // [buf][key][d]
  __shared__ __align__(16) u16 Klo[2][64][32];
  __shared__ __align__(16) u16 Vs [2][32][64];   // [buf][d][key], key-octet ^ (d&7)
  const int tid = threadIdx.x, wid = tid >> 6, lane = tid & 63;
  const int lm = lane & 15, quad = lane >> 4;
  const int bid = blockIdx.x;
  const int chunk = (CHUNKS > 1) ? (bid >> 9) : 0;
  const int qblk = bid & 31, bh = (bid >> 5) & 15;
  const int b = bh >> 3, h = bh & 7;
  const int q0 = qblk * 64 + wid * 16;
  const size_t tb = (size_t)b * 2048;
  const int NT = 32 / CHUNKS;                    // K-tiles per block
  const int kofs = chunk * (2048 / CHUNKS);      // first key of this chunk

  short8 qh, ql;   // Q^T B-frag (k=d=quad*8+j, n=qrow=lm)
  { size_t off = (tb + q0 + lm) * 256 + h * 32 + quad * 8;
    qh = *(const short8*)&qhi[off];
    ql = *(const short8*)&qlo[off]; }

  const int kkey = tid >> 2, kg = tid & 3;                  // K: [key][d-octet]
  const size_t kb = (tb + kofs + kkey) * 256 + h * 32 + kg * 8;
  const int vd = tid >> 3, vp = tid & 7, vk8 = vp ^ (vd & 7);
  const size_t vb = (size_t)(bh * 32 + vd) * 2048 + kofs + vk8 * 8;

  gll16(khi + kb, (u16*)Khi + tid * 8);
  gll16(klo + kb, (u16*)Klo + tid * 8);
  gll16(vt  + vb, (u16*)Vs  + tid * 8);

  float mrun = -1e30f, lrun = 0.f;
  floatx4 o0 = {0.f,0.f,0.f,0.f}, o1 = {0.f,0.f,0.f,0.f};

  for (int kt = 0; kt < NT; ++kt) {
    const int buf = kt & 1;
    __syncthreads();             // implicit vmcnt(0): tile kt resident
    if (kt < NT - 1) {           // stage kt+1 -> buf^1
      const int nb = (buf ^ 1) * 2048;
      const size_t ko = (size_t)(kt + 1) * 16384;
      const size_t vo = (size_t)(kt + 1) * 64;
      gll16(khi + kb + ko, (u16*)Khi + nb + tid * 8);
      gll16(klo + kb + ko, (u16*)Klo + nb + tid * 8);
      gll16(vt  + vb + vo, (u16*)Vs  + nb + tid * 8);
    }

    floatx4 z[4];
#pragma unroll
    for (int kf = 0; kf < 4; ++kf) {
      short8 khf = *(const short8*)&Khi[buf][kf * 16 + lm][quad * 8];
      short8 klf = *(const short8*)&Klo[buf][kf * 16 + lm][quad * 8];
      floatx4 zz = {0.f,0.f,0.f,0.f};
      zz = MFMA32(khf, ql, zz);
      zz = MFMA32(klf, qh, zz);
      zz = MFMA32(khf, qh, zz);
      z[kf] = zz;
    }
    float zm = fmaxf(fmaxf(fmaxf(z[0][0], z[0][1]), fmaxf(z[0][2], z[0][3])),
               fmaxf(fmaxf(z[1][0], z[1][1]), fmaxf(z[1][2], z[1][3])));
    zm = fmaxf(zm, fmaxf(fmaxf(fmaxf(z[2][0], z[2][1]), fmaxf(z[2][2], z[2][3])),
                   fmaxf(fmaxf(z[3][0], z[3][1]), fmaxf(z[3][2], z[3][3]))));
    zm = fmaxf(zm, __shfl_xor(zm, 16));
    zm = fmaxf(zm, __shfl_xor(zm, 32));
    const float mn = fmaxf(mrun, zm);
    const float alpha = exp2f((mrun - mn) * CLF);
    const float mc = mn * CLF;
    mrun = mn;
    float ls = 0.f;
    bf16x4 pb[4];
#pragma unroll
    for (int kf = 0; kf < 4; ++kf)
#pragma unroll
      for (int r = 0; r < 4; ++r) {
        const float p = exp2f(__builtin_fmaf(z[kf][r], CLF, -mc));
        ls += p;
        pb[kf][r] = (short)f2bf(p);
      }
    ls += __shfl_xor(ls, 16);
    ls += __shfl_xor(ls, 32);
    lrun = lrun * alpha + ls;
#pragma unroll
    for (int r = 0; r < 4; ++r) { o0[r] *= alpha; o1[r] *= alpha; }
    const u16* vbase = (const u16*)Vs + buf * 2048;
#pragma unroll
    for (int kf = 0; kf < 4; ++kf) {
      const int k8 = 2 * kf + (quad >> 1);
      const int d0 = lm, d1 = 16 + lm;
      bf16x4 vf0 = *(const bf16x4*)(vbase + (d0 * 8 + (k8 ^ (d0 & 7))) * 8 + (quad & 1) * 4);
      bf16x4 vf1 = *(const bf16x4*)(vbase + (d1 * 8 + (k8 ^ (d1 & 7))) * 8 + (quad & 1) * 4);
      o0 = MFMAPV(vf0, pb[kf], o0);
      o1 = MFMAPV(vf1, pb[kf], o1);
    }
  }
  const float inv = 1.0f / lrun;
  const size_t tok = tb + q0 + lm;
  u16* dst = ((CHUNKS > 2 && chunk >= 2) ? out23 : outp) + (size_t)(chunk & 1) * 1048576;
  const size_t rowo = tok * 256 + h * 32;
#pragma unroll
  for (int r = 0; r < 4; ++r) {
    dst[rowo + quad * 4 + r]      = f2bf(o0[r] * inv);
    dst[rowo + 16 + quad * 4 + r] = f2bf(o1[r] * inv);
  }
  if (CHUNKS > 1 && quad == 0)
    mu[chunk * 32768 + tok * 8 + h] = __builtin_fmaf(mrun, CLF, __log2f(lrun));
}

// ---------------- combine: softmax-weighted merge of CHUNKS key-chunks (into d) ----
template<int CHUNKS>
__global__ __launch_bounds__(256) void combine_k(u16* __restrict__ d,
                                                 const u16* __restrict__ e,
                                                 const float* __restrict__ mu)
{
  const int t = blockIdx.x, c = threadIdx.x, h = c >> 5;
  const size_t o = (size_t)t * 256 + c;
  float m[CHUNKS];
  float M = -1e30f;
#pragma unroll
  for (int i = 0; i < CHUNKS; ++i) { m[i] = mu[i * 32768 + t * 8 + h]; M = fmaxf(M, m[i]); }
  float wsum = 0.f, acc = 0.f;
#pragma unroll
  for (int i = 0; i < CHUNKS; ++i) {
    const float w = exp2f(m[i] - M);
    const u16 v = (i < 2) ? d[o + (size_t)i * 1048576] : e[o + (size_t)(i - 2) * 1048576];
    wsum += w; acc += w * bf2f(v);
  }
  d[o] = f2bf(acc / wsum);
}

// ---------------- residual add + LayerNorm: net = LN(projf + x) ----------------
__global__ __launch_bounds__(256) void ln_k(const float* __restrict__ pf,
                                            const u16* __restrict__ xh,
                                            const u16* __restrict__ xl,
                                            const u16* __restrict__ g,
                                            const u16* __restrict__ bta,
                                            u16* __restrict__ net)
{
  const int t = blockIdx.x, c = threadIdx.x;
  const size_t o = (size_t)t * 256 + c;
  float v = pf[o] + bf2f(xh[o]) + bf2f(xl[o]);
  float s = v, s2 = v * v;
#pragma unroll
  for (int d = 1; d < 64; d <<= 1) { s += __shfl_xor(s, d); s2 += __shfl_xor(s2, d); }
  __shared__ float ss[4], ss2[4];
  const int w = c >> 6;
  if ((c & 63) == 0) { ss[w] = s; ss2[w] = s2; }
  __syncthreads();
  s = ss[0] + ss[1] + ss[2] + ss[3];
  s2 = ss2[0] + ss2[1] + ss2[2] + ss2[3];
  const float mu = s * (1.f / 256.f);
  const float var = s2 * (1.f / 256.f) - mu * mu;
  const float is = rsqrtf(var + 1e-5f);
  net[o] = f2bf((v - mu) * is * bf2f(g[c]) + bf2f(bta[c]));
}

extern "C" void kernel_launch(void* const* d_in, const int* in_sizes, int n_in,
                              void* d_out, int out_size, void* d_ws, size_t ws_size,
                              hipStream_t stream) {
  const void* x      = d_in[0];
  const void* qkv_w  = d_in[1];
  const void* proj_w = d_in[2];
  const void* proj_b = d_in[3];
  const void* fc1_w  = d_in[4];
  const void* fc1_b  = d_in[5];
  const void* fc2_w  = d_in[6];
  const void* fc2_b  = d_in[7];
  const void* ln_g   = d_in[8];
  const void* ln_b   = d_in[9];

  char* ws = (char*)d_ws;
  u16* b_proj  = (u16*)(ws + 4096);
  u16* b_fc1   = (u16*)(ws + 8192);
  u16* b_fc2   = (u16*)(ws + 12288);
  u16* g_ln    = (u16*)(ws + 16384);
  u16* bb_ln   = (u16*)(ws + 20480);
  u16* wq_hi   = (u16*)(ws + 131072);    // [768][256]
  u16* wq_lo   = (u16*)(ws + 524288);
  u16* wt_proj = (u16*)(ws + 917504);    // [256][256]
  u16* wt_fc1  = (u16*)(ws + 1048576);   // [1024][256]
  u16* wt_fc2  = (u16*)(ws + 1572864);   // [256][1024]
  u16* x_hi    = (u16*)(ws + 2097152);   // [4096][256]
  u16* x_lo    = (u16*)(ws + 4194304);
  u16* q_hi    = (u16*)(ws + 6291456);
  u16* q_lo    = (u16*)(ws + 8388608);
  u16* k_hi    = (u16*)(ws + 10485760);
  u16* k_lo    = (u16*)(ws + 12582912);
  u16* vt      = (u16*)(ws + 14680064);  // [16 bh][32 d][2048 n]; end 16M
  float* mu    = (float*)(ws + 16777216);// up to [4][4096][8] fp32, 512KB
  u16* out23   = (u16*)(ws + 17301504);  // chunks 2,3 scratch, 4MB (end ~21.5M)
  u16* attn    = (u16*)d_out;            // d_out = chunks 0,1 (2 x 2MB bf16)
  float* projf = (float*)(ws + 6291456); // 4MB fp32 over dead Q
  u16* net     = (u16*)(ws + 14680064);  // 2MB over dead vt
  u16* hbuf    = (u16*)(ws + 2097152);   // 8MB over dead x/projf

  const bool sk4 = ws_size >= (17301504 + 4194304);    // call-invariant -> graph-safe
  const bool sk2 = ws_size >= (16777216 + 262144);

  prep_k<<<7176, 256, 0, stream>>>(x, qkv_w, proj_w, fc1_w, fc2_w,
                                   proj_b, fc1_b, fc2_b, ln_g, ln_b,
                                   x_hi, x_lo, wq_hi, wq_lo, wt_proj, wt_fc1, wt_fc2,
                                   b_proj, b_fc1, b_fc2, g_ln, bb_ln);

  // qkv = x @ qkv_w, 3-term hi/lo (V cols plain) -> q hi/lo, k hi/lo, vt
  gemm_k<2, 2, false, false, true><<<dim3(12, 64), 256, 0, stream>>>(
      x_hi, wq_hi, x_lo, wq_lo, nullptr, nullptr, vt, q_hi, q_lo, k_hi, k_lo, 4096, 768, 256);
  if (sk4) {
    attn_k<4><<<2048, 256, 0, stream>>>(q_hi, q_lo, k_hi, k_lo, vt, attn, out23, mu);
    combine_k<4><<<4096, 256, 0, stream>>>(attn, out23, mu);
  } else if (sk2) {
    attn_k<2><<<1024, 256, 0, stream>>>(q_hi, q_lo, k_hi, k_lo, vt, attn, nullptr, mu);
    combine_k<2><<<4096, 256, 0, stream>>>(attn, nullptr, mu);
  } else {
    attn_k<1><<<512, 256, 0, stream>>>(q_hi, q_lo, k_hi, k_lo, vt, attn, nullptr, nullptr);
  }
  // proj (+bias) -> fp32
  gemm_k<2, 0, true, false, false><<<dim3(4, 64), 256, 0, stream>>>(
      attn, wt_proj, nullptr, nullptr, b_proj, nullptr, projf,
      nullptr, nullptr, nullptr, nullptr, 4096, 256, 256);
  ln_k<<<4096, 256, 0, stream>>>(projf, x_hi, x_lo, g_ln, bb_ln, net);
  // fc1 (+bias)
  gemm_k<2, 1, true, false, false><<<dim3(16, 64), 256, 0, stream>>>(
      net, wt_fc1, nullptr, nullptr, b_fc1, nullptr, hbuf,
      nullptr, nullptr, nullptr, nullptr, 4096, 1024, 256);
  // fc2 (+bias +shortcut) -> d_out fp32
  gemm_k<2, 0, true, true, false><<<dim3(4, 64), 256, 0, stream>>>(
      hbuf, wt_fc2, nullptr, nullptr, b_fc2, net, d_out,
      nullptr, nullptr, nullptr, nullptr, 4096, 256, 1024);
}

// Round 12
// 163.674 us; speedup vs baseline: 4.0065x; 1.0358x over previous
//
#include <hip/hip_runtime.h>

// B=2,N=2048,D=256,H=8,HD=32,DFF=1024. SCALE MULTIPLIES by sqrt(32). No MLP
// activation. Post-norm. Inputs fp32 (auto-detected), output fp32.
// Verified R5-R11: absmax 0.031 vs threshold 0.134.
//
// R12: attn is VALU-bound (VALUBusy 66%, MfmaUtil 17%). (1) exp2 via
// __builtin_amdgcn_exp2f; P packed via v_perm_b32 pairs (round-half-up).
// (2) proj GEMM fuses the 4-way split-K combine into A-staging (kills
// combine_k launch). (3) qkv V-epilogue: C -> LDS transpose -> coalesced
// 16B vt stores (was 1024 scattered 2B stores/wave).

typedef __attribute__((ext_vector_type(8))) short short8;   // 8 bf16 = 4 VGPRs
typedef __attribute__((ext_vector_type(4))) short bf16x4;   // 4 bf16 = 2 VGPRs
typedef __attribute__((ext_vector_type(4))) float floatx4;
typedef __attribute__((ext_vector_type(2))) unsigned int uint2v;
typedef unsigned short u16;

#define MFMA32(a,b,c) __builtin_amdgcn_mfma_f32_16x16x32_bf16((a),(b),(c),0,0,0)
#if __has_builtin(__builtin_amdgcn_mfma_f32_16x16x16_bf16)
#define MFMAPV(a,b,c) __builtin_amdgcn_mfma_f32_16x16x16_bf16((a),(b),(c),0,0,0)
#else
#define MFMAPV(a,b,c) __builtin_amdgcn_mfma_f32_16x16x16bf16_1k((a),(b),(c),0,0,0)
#endif
#define CLF 8.1615404f   // SCALE * log2(e)

#if __has_builtin(__builtin_amdgcn_exp2f)
#define EX2(x) __builtin_amdgcn_exp2f(x)
#else
#define EX2(x) exp2f(x)
#endif

__device__ __forceinline__ float bf2f(u16 u) { return __uint_as_float(((unsigned)u) << 16); }
__device__ __forceinline__ u16 f2bf(float f) {            // RNE
  unsigned u = __float_as_uint(f);
  u += 0x7fffu + ((u >> 16) & 1u);
  return (u16)(u >> 16);
}
// pack 2 fp32 -> 2 bf16 (round-half-up), 3 VALU: [bf(b):bf(a)]
__device__ __forceinline__ unsigned pkbf2(float a, float b) {
#if __has_builtin(__builtin_amdgcn_perm)
  return __builtin_amdgcn_perm(__float_as_uint(b) + 0x8000u,
                               __float_as_uint(a) + 0x8000u, 0x07060302u);
#else
  return (unsigned)f2bf(a) | ((unsigned)f2bf(b) << 16);
#endif
}
// async global->LDS, 16B/lane; LDS dest = wave-uniform base + lane*16 (m104)
__device__ __forceinline__ void gll16(const void* g, void* l) {
  __builtin_amdgcn_global_load_lds((const __attribute__((address_space(1))) void*)g,
                                   (__attribute__((address_space(3))) void*)l, 16, 0, 0);
}

// ---------------- fused preamble: dtype-detect + canonicalize all inputs ----------------
__global__ __launch_bounds__(256) void prep_k(
    const void* __restrict__ x, const void* __restrict__ qkv_w,
    const void* __restrict__ proj_w, const void* __restrict__ fc1_w,
    const void* __restrict__ fc2_w, const void* __restrict__ proj_b,
    const void* __restrict__ fc1_b, const void* __restrict__ fc2_b,
    const void* __restrict__ ln_g, const void* __restrict__ ln_b,
    u16* __restrict__ x_hi, u16* __restrict__ x_lo,
    u16* __restrict__ wq_hi, u16* __restrict__ wq_lo,
    u16* __restrict__ wt_proj, u16* __restrict__ wt_fc1, u16* __restrict__ wt_fc2,
    u16* __restrict__ b_proj, u16* __restrict__ b_fc1, u16* __restrict__ b_fc2,
    u16* __restrict__ g_ln, u16* __restrict__ bb_ln)
{
  const int lane = threadIdx.x & 63;
  const float probe = bf2f(((const u16*)qkv_w)[lane]);
  const bool f32 = __ballot(!(fabsf(probe) < 1000.0f)) != 0ull;
  const int bid = blockIdx.x, tid = threadIdx.x;
  #define RD(p, i) (f32 ? ((const float*)(p))[i] : bf2f(((const u16*)(p))[i]))
  if (bid < 4096) {               // x -> hi+lo
    const size_t i = (size_t)bid * 256 + tid;
    const float f = RD(x, i); const u16 h = f2bf(f);
    x_hi[i] = h; x_lo[i] = f2bf(f - bf2f(h));
  } else if (bid < 4864) {        // qkv_w^T -> hi+lo ([768][256])
    const int idx = (bid - 4096) * 256 + tid;
    const int n = idx >> 8, k = idx & 255;
    const float f = RD(qkv_w, (size_t)k * 768 + n); const u16 h = f2bf(f);
    wq_hi[idx] = h; wq_lo[idx] = f2bf(f - bf2f(h));
  } else if (bid < 5120) {        // proj_w^T ([256][256])
    const int idx = (bid - 4864) * 256 + tid;
    wt_proj[idx] = f2bf(RD(proj_w, (size_t)(idx & 255) * 256 + (idx >> 8)));
  } else if (bid < 6144) {        // fc1_w^T ([1024][256])
    const int idx = (bid - 5120) * 256 + tid;
    wt_fc1[idx] = f2bf(RD(fc1_w, (size_t)(idx & 255) * 1024 + (idx >> 8)));
  } else if (bid < 7168) {        // fc2_w^T ([256][1024])
    const int idx = (bid - 6144) * 256 + tid;
    wt_fc2[idx] = f2bf(RD(fc2_w, (size_t)(idx & 1023) * 256 + (idx >> 10)));
  } else {                        // biases + LN params
    const int j = (bid - 7168) * 256 + tid;
    if (j < 256)       b_proj[j]        = f2bf(RD(proj_b, j));
    else if (j < 1280) b_fc1[j - 256]   = f2bf(RD(fc1_b, j - 256));
    else if (j < 1536) b_fc2[j - 1280]  = f2bf(RD(fc2_b, j - 1280));
    else if (j < 1792) g_ln[j - 1536]   = f2bf(RD(ln_g, j - 1536));
    else               bb_ln[j - 1792]  = f2bf(RD(ln_b, j - 1792));
  }
  #undef RD
}

// ---------------- GEMM with register-prefetch staging ----------------
// COMB: A is 4-chunk split-K attention output (A=chunks 0,1; A2=chunks 2,3);
// staging combines on the fly with log2-domain weights from muc.
template<int TW, int EPI, bool BIAS, bool RES, bool SPLIT, bool COMB>
__global__ __launch_bounds__(256) void gemm_k(
    const u16* __restrict__ A, const u16* __restrict__ Bt,
    const u16* __restrict__ A2, const u16* __restrict__ B2,
    const u16* __restrict__ bias, const u16* __restrict__ res,
    void* __restrict__ out0, u16* __restrict__ aux1, u16* __restrict__ aux2,
    u16* __restrict__ aux3, u16* __restrict__ aux4, const float* __restrict__ muc,
    int M, int Nn, int K)
{
  constexpr int BT = TW * 32;
  constexpr int NC = (TW > 1 ? TW / 2 : 1);
  __shared__ __align__(16) short As[BT][40];
  __shared__ __align__(16) short Bs[BT][40];
  __shared__ __align__(16) short As2[SPLIT ? BT : 1][40];
  __shared__ __align__(16) short Bs2[SPLIT ? BT : 1][40];
  __shared__ __align__(16) u16 Vt[(EPI == 2) ? 64 * 72 : 1];   // V transpose staging
  const int tid = threadIdx.x;
  const int m0 = blockIdx.y * BT, n0 = blockIdx.x * BT;
  const bool sp = SPLIT && (n0 < 512);
  const int wid = tid >> 6, lane = tid & 63;
  const int wm = (wid >> 1) * (TW * 16), wn = (wid & 1) * (TW * 16);
  const int lm = lane & 15, quad = lane >> 4;

  floatx4 zero = {0.f, 0.f, 0.f, 0.f};
  floatx4 acc[TW][TW];
#pragma unroll
  for (int i = 0; i < TW; ++i)
#pragma unroll
    for (int j = 0; j < TW; ++j) acc[i][j] = zero;

  int srow[NC], soff[NC];
#pragma unroll
  for (int c = 0; c < NC; ++c) {
    const int cid = tid * NC + c;
    srow[c] = cid >> 2; soff[c] = (cid & 3) * 8;
  }

  // COMB helper: combined A load of 8 cols at (t, col8)
  auto comb8 = [&](int t, int col8) -> short8 {
    const size_t o = (size_t)t * 256 + col8;
    const int h = col8 >> 5;
    const float m0_ = muc[t * 8 + h],          m1_ = muc[32768 + t * 8 + h];
    const float m2_ = muc[65536 + t * 8 + h],  m3_ = muc[98304 + t * 8 + h];
    const float M = fmaxf(fmaxf(m0_, m1_), fmaxf(m2_, m3_));
    float w0 = EX2(m0_ - M), w1 = EX2(m1_ - M), w2 = EX2(m2_ - M), w3 = EX2(m3_ - M);
    const float inv = 1.f / (w0 + w1 + w2 + w3);
    w0 *= inv; w1 *= inv; w2 *= inv; w3 *= inv;
    short8 a0 = *(const short8*)&A[o],  a1 = *(const short8*)&A[o + 1048576];
    short8 a2 = *(const short8*)&A2[o], a3 = *(const short8*)&A2[o + 1048576];
    float v[8];
#pragma unroll
    for (int j = 0; j < 8; ++j)
      v[j] = w0 * bf2f(a0[j]) + w1 * bf2f(a1[j]) + w2 * bf2f(a2[j]) + w3 * bf2f(a3[j]);
    uint2v uu0 = {pkbf2(v[0], v[1]), pkbf2(v[2], v[3])};
    uint2v uu1 = {pkbf2(v[4], v[5]), pkbf2(v[6], v[7])};
    short8 r;
    *(uint2v*)&r = uu0; *((uint2v*)&r + 1) = uu1;
    return r;
  };

  short8 ra[NC], rb[NC], ra2[NC], rb2[NC];
#pragma unroll
  for (int c = 0; c < NC; ++c) {        // prefetch tile 0
    const size_t gb = (size_t)(n0 + srow[c]) * K + soff[c];
    rb[c] = *(const short8*)&Bt[gb];
    if (COMB) ra[c] = comb8(m0 + srow[c], soff[c]);
    else      ra[c] = *(const short8*)&A[(size_t)(m0 + srow[c]) * K + soff[c]];
    if (sp) {
      ra2[c] = *(const short8*)&A2[(size_t)(m0 + srow[c]) * K + soff[c]];
      rb2[c] = *(const short8*)&B2[gb];
    }
  }

  for (int k0 = 0; k0 < K; k0 += 32) {
    if (k0) __syncthreads();
#pragma unroll
    for (int c = 0; c < NC; ++c) {
      *(short8*)&As[srow[c]][soff[c]] = ra[c];
      *(short8*)&Bs[srow[c]][soff[c]] = rb[c];
      if (sp) {
        *(short8*)&As2[srow[c]][soff[c]] = ra2[c];
        *(short8*)&Bs2[srow[c]][soff[c]] = rb2[c];
      }
    }
    __syncthreads();
    if (k0 + 32 < K) {                   // next-tile loads fly during MFMAs
#pragma unroll
      for (int c = 0; c < NC; ++c) {
        const size_t gb = (size_t)(n0 + srow[c]) * K + k0 + 32 + soff[c];
        rb[c] = *(const short8*)&Bt[gb];
        if (COMB) ra[c] = comb8(m0 + srow[c], k0 + 32 + soff[c]);
        else      ra[c] = *(const short8*)&A[(size_t)(m0 + srow[c]) * K + k0 + 32 + soff[c]];
        if (sp) {
          ra2[c] = *(const short8*)&A2[(size_t)(m0 + srow[c]) * K + k0 + 32 + soff[c]];
          rb2[c] = *(const short8*)&B2[gb];
        }
      }
    }
    short8 fa[TW], fb[TW], fa2[TW], fb2[TW];
#pragma unroll
    for (int t = 0; t < TW; ++t) {
      fa[t] = *(const short8*)&As[wm + t * 16 + lm][quad * 8];
      fb[t] = *(const short8*)&Bs[wn + t * 16 + lm][quad * 8];
      if (sp) {
        fa2[t] = *(const short8*)&As2[wm + t * 16 + lm][quad * 8];
        fb2[t] = *(const short8*)&Bs2[wn + t * 16 + lm][quad * 8];
      }
    }
#pragma unroll
    for (int i = 0; i < TW; ++i)
#pragma unroll
      for (int j = 0; j < TW; ++j) {
        if (sp) {
          acc[i][j] = MFMA32(fa[i], fb2[j], acc[i][j]);
          acc[i][j] = MFMA32(fa2[i], fb[j], acc[i][j]);
        }
        acc[i][j] = MFMA32(fa[i], fb[j], acc[i][j]);
      }
  }

  // ---- V epilogue (qkv, n0>=512): C -> LDS transpose -> coalesced vt rows ----
  if (EPI == 2 && n0 >= 512) {
    __syncthreads();                      // all waves done with As/Bs & MFMAs
#pragma unroll
    for (int i = 0; i < TW; ++i)
#pragma unroll
      for (int j = 0; j < TW; ++j)
#pragma unroll
        for (int r = 0; r < 4; ++r)
          Vt[(wn + j * 16 + lm) * 72 + wm + i * 16 + quad * 4 + r] = f2bf(acc[i][j][r]);
    __syncthreads();
    const int bb = m0 >> 11, n = m0 & 2047;
#pragma unroll
    for (int pass = 0; pass < 2; ++pass) {
      const int dl = (tid >> 3) + pass * 32;     // local col 0..63
      const int oct = tid & 7;                   // token octet
      const int col = n0 - 512 + dl;             // 0..255
      const int d = col & 31, hh = col >> 5;
      short8 v = *(const short8*)&Vt[dl * 72 + oct * 8];
      *(short8*)&((u16*)out0)[(size_t)((bb * 8 + hh) * 32 + d) * 2048 + n + oct * 8] = v;
    }
    return;
  }

#pragma unroll
  for (int i = 0; i < TW; ++i) {
    const int rowb = m0 + wm + i * 16 + quad * 4;
#pragma unroll
    for (int j = 0; j < TW; ++j) {
      const int col = n0 + wn + j * 16 + lm;
      const float bv = BIAS ? bf2f(bias[col]) : 0.f;
#pragma unroll
      for (int r = 0; r < 4; ++r) {
        const int row = rowb + r;
        float v = acc[i][j][r] + bv;
        const size_t o = (size_t)row * Nn + col;
        if (RES) v += bf2f(res[o]);
        if (EPI == 0) {
          ((float*)out0)[o] = v;
        } else if (EPI == 1) {
          ((u16*)out0)[o] = f2bf(v);
        } else {
          u16 hi = f2bf(v);
          u16 lo = f2bf(v - bf2f(hi));
          if (col < 256) {
            const size_t oq = (size_t)row * 256 + col;
            aux1[oq] = hi; aux2[oq] = lo;       // Q
          } else {
            const size_t ok = (size_t)row * 256 + (col - 256);
            aux3[ok] = hi; aux4[ok] = lo;       // K
          }
        }
      }
    }
  }
}

// ---------------- flash attention: split-K x CHUNKS, S^T form, register-direct P ----
template<int CHUNKS>
__global__ __launch_bounds__(256) void attn_k(
    const u16* __restrict__ qhi, const u16* __restrict__ qlo,
    const u16* __restrict__ khi, const u16* __restrict__ klo,
    const u16* __restrict__ vt, u16* __restrict__ outp, u16* __restrict__ out23,
    float* __restrict__ mu)
{
  __shared__ __align__(16) u16 Khi[2][64][32];   // [buf][key][d]
  __shared__ __align__(16) u16 Klo[2][64][32];
  __shared__ __align__(16) u16 Vs [2][32][64];   // [buf][d][key], key-octet ^ (d&7)
  const int tid = threadIdx.x, wid = tid >> 6, lane = tid & 63;
  const int lm = lane & 15, quad = lane >> 4;
  const int bid = blockIdx.x;
  const int chunk = (CHUNKS > 1) ? (bid >> 9) : 0;
  const int qblk = bid & 31, bh = (bid >> 5) & 15;
  const int b = bh >> 3, h = bh & 7;
  const int q0 = qblk * 64 + wid * 16;
  const size_t tb = (size_t)b * 2048;
  const int NT = 32 / CHUNKS;
  const int kofs = chunk * (2048 / CHUNKS);

  short8 qh, ql;   // Q^T B-frag (k=d=quad*8+j, n=qrow=lm)
  { size_t off = (tb + q0 + lm) * 256 + h * 32 + quad * 8;
    qh = *(const short8*)&qhi[off];
    ql = *(const short8*)&qlo[off]; }

  const int kkey = tid >> 2, kg = tid & 3;
  const size_t kb = (tb + kofs + kkey) * 256 + h * 32 + kg * 8;
  const int vd = tid >> 3, vp = tid & 7, vk8 = vp ^ (vd & 7);
  const size_t vb = (size_t)(bh * 32 + vd) * 2048 + kofs + vk8 * 8;

  gll16(khi + kb, (u16*)Khi + tid * 8);
  gll16(klo + kb, (u16*)Klo + tid * 8);
  gll16(vt  + vb, (u16*)Vs  + tid * 8);

  float mrun = -1e30f, lrun = 0.f;
  floatx4 o0 = {0.f,0.f,0.f,0.f}, o1 = {0.f,0.f,0.f,0.f};

  for (int kt = 0; kt < NT; ++kt) {
    const int buf = kt & 1;
    __syncthreads();
    if (kt < NT - 1) {
      const int nb = (buf ^ 1) * 2048;
      const size_t ko = (size_t)(kt + 1) * 16384;
      const size_t vo = (size_t)(kt + 1) * 64;
      gll16(khi + kb + ko, (u16*)Khi + nb + tid * 8);
      gll16(klo + kb + ko, (u16*)Klo + nb + tid * 8);
      gll16(vt  + vb + vo, (u16*)Vs  + nb + tid * 8);
    }

    floatx4 z[4];
#pragma unroll
    for (int kf = 0; kf < 4; ++kf) {
      short8 khf = *(const short8*)&Khi[buf][kf * 16 + lm][quad * 8];
      short8 klf = *(const short8*)&Klo[buf][kf * 16 + lm][quad * 8];
      floatx4 zz = {0.f,0.f,0.f,0.f};
      zz = MFMA32(khf, ql, zz);
      zz = MFMA32(klf, qh, zz);
      zz = MFMA32(khf, qh, zz);
      z[kf] = zz;
    }
    float zm = fmaxf(fmaxf(fmaxf(z[0][0], z[0][1]), fmaxf(z[0][2], z[0][3])),
               fmaxf(fmaxf(z[1][0], z[1][1]), fmaxf(z[1][2], z[1][3])));
    zm = fmaxf(zm, fmaxf(fmaxf(fmaxf(z[2][0], z[2][1]), fmaxf(z[2][2], z[2][3])),
                   fmaxf(fmaxf(z[3][0], z[3][1]), fmaxf(z[3][2], z[3][3]))));
    zm = fmaxf(zm, __shfl_xor(zm, 16));
    zm = fmaxf(zm, __shfl_xor(zm, 32));
    const float mn = fmaxf(mrun, zm);
    const float alpha = EX2((mrun - mn) * CLF);
    const float mc = mn * CLF;
    mrun = mn;
    float ls = 0.f;
    bf16x4 pb[4];
#pragma unroll
    for (int kf = 0; kf < 4; ++kf) {
      const float p0 = EX2(__builtin_fmaf(z[kf][0], CLF, -mc));
      const float p1 = EX2(__builtin_fmaf(z[kf][1], CLF, -mc));
      const float p2 = EX2(__builtin_fmaf(z[kf][2], CLF, -mc));
      const float p3 = EX2(__builtin_fmaf(z[kf][3], CLF, -mc));
      ls += (p0 + p1) + (p2 + p3);
      uint2v uu = {pkbf2(p0, p1), pkbf2(p2, p3)};
      pb[kf] = *(bf16x4*)&uu;
    }
    ls += __shfl_xor(ls, 16);
    ls += __shfl_xor(ls, 32);
    lrun = lrun * alpha + ls;
#pragma unroll
    for (int r = 0; r < 4; ++r) { o0[r] *= alpha; o1[r] *= alpha; }
    const u16* vbase = (const u16*)Vs + buf * 2048;
#pragma unroll
    for (int kf = 0; kf < 4; ++kf) {
      const int k8 = 2 * kf + (quad >> 1);
      const int d0 = lm, d1 = 16 + lm;
      bf16x4 vf0 = *(const bf16x4*)(vbase + (d0 * 8 + (k8 ^ (d0 & 7))) * 8 + (quad & 1) * 4);
      bf16x4 vf1 = *(const bf16x4*)(vbase + (d1 * 8 + (k8 ^ (d1 & 7))) * 8 + (quad & 1) * 4);
      o0 = MFMAPV(vf0, pb[kf], o0);
      o1 = MFMAPV(vf1, pb[kf], o1);
    }
  }
  const float inv = 1.0f / lrun;
  const size_t tok = tb + q0 + lm;
  u16* dst = ((CHUNKS > 2 && chunk >= 2) ? out23 : outp) + (size_t)(chunk & 1) * 1048576;
  const size_t rowo = tok * 256 + h * 32;
#pragma unroll
  for (int r = 0; r < 4; ++r) {
    dst[rowo + quad * 4 + r]      = f2bf(o0[r] * inv);
    dst[rowo + 16 + quad * 4 + r] = f2bf(o1[r] * inv);
  }
  if (CHUNKS > 1 && quad == 0)
    mu[chunk * 32768 + tok * 8 + h] = __builtin_fmaf(mrun, CLF, __log2f(lrun));
}

// ---------------- combine (fallback, sk2 path only) ----------------
template<int CHUNKS>
__global__ __launch_bounds__(256) void combine_k(u16* __restrict__ d,
                                                 const u16* __restrict__ e,
                                                 const float* __restrict__ mu)
{
  const int t = blockIdx.x, c = threadIdx.x, h = c >> 5;
  const size_t o = (size_t)t * 256 + c;
  float m[CHUNKS];
  float M = -1e30f;
#pragma unroll
  for (int i = 0; i < CHUNKS; ++i) { m[i] = mu[i * 32768 + t * 8 + h]; M = fmaxf(M, m[i]); }
  float wsum = 0.f, acc = 0.f;
#pragma unroll
  for (int i = 0; i < CHUNKS; ++i) {
    const float w = EX2(m[i] - M);
    const u16 v = (i < 2) ? d[o + (size_t)i * 1048576] : e[o + (size_t)(i - 2) * 1048576];
    wsum += w; acc += w * bf2f(v);
  }
  d[o] = f2bf(acc / wsum);
}

// ---------------- residual add + LayerNorm: net = LN(projf + x) ----------------
__global__ __launch_bounds__(256) void ln_k(const float* __restrict__ pf,
                                            const u16* __restrict__ xh,
                                            const u16* __restrict__ xl,
                                            const u16* __restrict__ g,
                                            const u16* __restrict__ bta,
                                            u16* __restrict__ net)
{
  const int t = blockIdx.x, c = threadIdx.x;
  const size_t o = (size_t)t * 256 + c;
  float v = pf[o] + bf2f(xh[o]) + bf2f(xl[o]);
  float s = v, s2 = v * v;
#pragma unroll
  for (int d = 1; d < 64; d <<= 1) { s += __shfl_xor(s, d); s2 += __shfl_xor(s2, d); }
  __shared__ float ss[4], ss2[4];
  const int w = c >> 6;
  if ((c & 63) == 0) { ss[w] = s; ss2[w] = s2; }
  __syncthreads();
  s = ss[0] + ss[1] + ss[2] + ss[3];
  s2 = ss2[0] + ss2[1] + ss2[2] + ss2[3];
  const float mu = s * (1.f / 256.f);
  const float var = s2 * (1.f / 256.f) - mu * mu;
  const float is = rsqrtf(var + 1e-5f);
  net[o] = f2bf((v - mu) * is * bf2f(g[c]) + bf2f(bta[c]));
}

extern "C" void kernel_launch(void* const* d_in, const int* in_sizes, int n_in,
                              void* d_out, int out_size, void* d_ws, size_t ws_size,
                              hipStream_t stream) {
  const void* x      = d_in[0];
  const void* qkv_w  = d_in[1];
  const void* proj_w = d_in[2];
  const void* proj_b = d_in[3];
  const void* fc1_w  = d_in[4];
  const void* fc1_b  = d_in[5];
  const void* fc2_w  = d_in[6];
  const void* fc2_b  = d_in[7];
  const void* ln_g   = d_in[8];
  const void* ln_b   = d_in[9];

  char* ws = (char*)d_ws;
  u16* b_proj  = (u16*)(ws + 4096);
  u16* b_fc1   = (u16*)(ws + 8192);
  u16* b_fc2   = (u16*)(ws + 12288);
  u16* g_ln    = (u16*)(ws + 16384);
  u16* bb_ln   = (u16*)(ws + 20480);
  u16* wq_hi   = (u16*)(ws + 131072);    // [768][256]
  u16* wq_lo   = (u16*)(ws + 524288);
  u16* wt_proj = (u16*)(ws + 917504);    // [256][256]
  u16* wt_fc1  = (u16*)(ws + 1048576);   // [1024][256]
  u16* wt_fc2  = (u16*)(ws + 1572864);   // [256][1024]
  u16* x_hi    = (u16*)(ws + 2097152);   // [4096][256]
  u16* x_lo    = (u16*)(ws + 4194304);
  u16* q_hi    = (u16*)(ws + 6291456);
  u16* q_lo    = (u16*)(ws + 8388608);
  u16* k_hi    = (u16*)(ws + 10485760);
  u16* k_lo    = (u16*)(ws + 12582912);
  u16* vt      = (u16*)(ws + 14680064);  // [16 bh][32 d][2048 n]; end 16M
  float* mu    = (float*)(ws + 16777216);// [4][4096][8] fp32, 512KB
  u16* out23   = (u16*)(ws + 17301504);  // chunks 2,3 scratch, 4MB
  u16* attn    = (u16*)d_out;            // d_out = chunks 0,1 (2 x 2MB bf16)
  float* projf = (float*)(ws + 6291456); // 4MB fp32 over dead Q
  u16* net     = (u16*)(ws + 14680064);  // 2MB over dead vt
  u16* hbuf    = (u16*)(ws + 2097152);   // 8MB over dead x/projf

  const bool sk4 = ws_size >= (17301504 + 4194304);    // call-invariant -> graph-safe
  const bool sk2 = ws_size >= (16777216 + 262144);

  prep_k<<<7176, 256, 0, stream>>>(x, qkv_w, proj_w, fc1_w, fc2_w,
                                   proj_b, fc1_b, fc2_b, ln_g, ln_b,
                                   x_hi, x_lo, wq_hi, wq_lo, wt_proj, wt_fc1, wt_fc2,
                                   b_proj, b_fc1, b_fc2, g_ln, bb_ln);

  // qkv = x @ qkv_w, 3-term hi/lo (V cols plain) -> q hi/lo, k hi/lo, vt
  gemm_k<2, 2, false, false, true, false><<<dim3(12, 64), 256, 0, stream>>>(
      x_hi, wq_hi, x_lo, wq_lo, nullptr, nullptr, vt, q_hi, q_lo, k_hi, k_lo,
      nullptr, 4096, 768, 256);
  if (sk4) {
    attn_k<4><<<2048, 256, 0, stream>>>(q_hi, q_lo, k_hi, k_lo, vt, attn, out23, mu);
    // proj (+bias) with fused 4-way combine in A-staging -> fp32
    gemm_k<2, 0, true, false, false, true><<<dim3(4, 64), 256, 0, stream>>>(
        attn, wt_proj, out23, nullptr, b_proj, nullptr, projf,
        nullptr, nullptr, nullptr, nullptr, mu, 4096, 256, 256);
  } else if (sk2) {
    attn_k<2><<<1024, 256, 0, stream>>>(q_hi, q_lo, k_hi, k_lo, vt, attn, nullptr, mu);
    combine_k<2><<<4096, 256, 0, stream>>>(attn, nullptr, mu);
    gemm_k<2, 0, true, false, false, false><<<dim3(4, 64), 256, 0, stream>>>(
        attn, wt_proj, nullptr, nullptr, b_proj, nullptr, projf,
        nullptr, nullptr, nullptr, nullptr, nullptr, 4096, 256, 256);
  } else {
    attn_k<1><<<512, 256, 0, stream>>>(q_hi, q_lo, k_hi, k_lo, vt, attn, nullptr, nullptr);
    gemm_k<2, 0, true, false, false, false><<<dim3(4, 64), 256, 0, stream>>>(
        attn, wt_proj, nullptr, nullptr, b_proj, nullptr, projf,
        nullptr, nullptr, nullptr, nullptr, nullptr, 4096, 256, 256);
  }
  ln_k<<<4096, 256, 0, stream>>>(projf, x_hi, x_lo, g_ln, bb_ln, net);
  // fc1 (+bias)
  gemm_k<2, 1, true, false, false, false><<<dim3(16, 64), 256, 0, stream>>>(
      net, wt_fc1, nullptr, nullptr, b_fc1, nullptr, hbuf,
      nullptr, nullptr, nullptr, nullptr, nullptr, 4096, 1024, 256);
  // fc2 (+bias +shortcut) -> d_out fp32
  gemm_k<2, 0, true, true, false, false><<<dim3(4, 64), 256, 0, stream>>>(
      hbuf, wt_fc2, nullptr, nullptr, b_fc2, net, d_out,
      nullptr, nullptr, nullptr, nullptr, nullptr, 4096, 256, 1024);
}